// Round 8
// baseline (397.029 us; speedup 1.0000x reference)
//
#include <hip/hip_runtime.h>

// ECNR forward, R8.
//  Numerics identical to R7 (same bf16x2 splits, same 4-product MFMA, same
//  sin path) — only data movement & operand roles restructured.
//  K1 ecnr_dequant: 768 blocks x 512 thr, no staging transpose: coalesced
//     label reads -> LDS codebook gather -> perm-pack -> coalesced b128
//     stores. Planes chunk-major [16 c][128 n][8 k], lo|hi. w3 as bf16x2.
//  K2 ecnr_fwd: 8192 x 512 (8 waves, 4 blocks/CU). OPERAND SWAP: A = W
//     (global b128), B = H^T (LDS b128 from lo/hi planes -> zero unpack
//     VALU). Epilogue writes 4-consecutive-n groups as ds_write_b64.
//     L3 on MFMA (w3 bf16x2, 3 products). 7 barriers.

typedef unsigned int u32;
typedef unsigned short u16;
typedef __bf16 v8bf  __attribute__((ext_vector_type(8)));
typedef float  v16f  __attribute__((ext_vector_type(16)));
typedef u32    v4u   __attribute__((ext_vector_type(4)));
typedef u32    v2u   __attribute__((ext_vector_type(2)));

#define MFMA(a, b, c) __builtin_amdgcn_mfma_f32_32x32x16_bf16(a, b, c, 0, 0, 0)

// sin(30*pre) = v_sin(v_fract(pre * 30/2pi)) — same math as r5-r7.
__device__ __forceinline__ float sin_omega(float pre) {
    float rev = pre * 4.774648292756860f;
    return __builtin_amdgcn_sinf(__builtin_amdgcn_fractf(rev));
}

// fp32 -> packed bf16x2 (low16 = rne leading split, high16 = residual)
__device__ __forceinline__ u32 pack2(float c) {
    __bf16 b0 = (__bf16)c;
    float  f0 = (float)b0;
    __bf16 b1 = (__bf16)(c - f0);
    return (u32)__builtin_bit_cast(u16, b0) |
           ((u32)__builtin_bit_cast(u16, b1) << 16);
}

#define PLO(a, b) __builtin_amdgcn_perm((a), (b), 0x05040100u)  // b.lo16 | a.lo16<<16
#define PHI(a, b) __builtin_amdgcn_perm((a), (b), 0x07060302u)  // b.hi16 | a.hi16<<16

// ---------------------------------------------------------------------------
// K1: dequant. blocks 0..511: (m = blk>>1, L = blk&1) full 128x128 layer ->
// lo|hi planes, element (n,k) at (k>>3)*1024 + n*8 + (k&7) u16 (hi +16384).
// blocks 512..767: m = blk-512: W0 planes ([2 c][128 n][8 k], hi +2048) + w3
// (lo[128] | hi[128] u16).
// ---------------------------------------------------------------------------
__global__ __launch_bounds__(512)
void ecnr_dequant(const float* __restrict__ cent0, const int* __restrict__ lab0,
                  const float* __restrict__ cent1, const int* __restrict__ lab1,
                  const float* __restrict__ cent2, const int* __restrict__ lab2,
                  const float* __restrict__ cent3, const int* __restrict__ lab3,
                  u16* __restrict__ wpl1, u16* __restrict__ wpl2,
                  u16* __restrict__ w0pl, u16* __restrict__ w3pl)
{
    __shared__ u32 cpk[512];
    const int t = threadIdx.x;

    if (blockIdx.x < 512) {
        const int m = blockIdx.x >> 1, L = blockIdx.x & 1;
        if (t < 256) cpk[t] = pack2((L ? cent2 : cent1)[t]);
        __syncthreads();
        const int* lab = (L ? lab2 : lab1) + (size_t)m * 16384;
        u16* base = (L ? wpl2 : wpl1) + (size_t)m * 32768;
        #pragma unroll
        for (int i = 0; i < 4; ++i) {
            const int id = i * 512 + t;
            const int n = id & 127, c = id >> 7;
            u32 g[8];
            #pragma unroll
            for (int j = 0; j < 8; ++j) g[j] = cpk[lab[(8 * c + j) * 128 + n]];
            v4u lo, hi;
            #pragma unroll
            for (int r = 0; r < 4; ++r) {
                lo[r] = PLO(g[2 * r + 1], g[2 * r]);
                hi[r] = PHI(g[2 * r + 1], g[2 * r]);
            }
            *(v4u*)(base + c * 1024 + n * 8)         = lo;
            *(v4u*)(base + 16384 + c * 1024 + n * 8) = hi;
        }
    } else {
        const int m = blockIdx.x - 512;
        if (t < 256) cpk[t] = pack2(cent0[t]);
        else         cpk[t] = pack2(cent3[t - 256]);
        __syncthreads();
        if (t < 256) {
            const int n = t & 127, c = t >> 7;
            const int* lab = lab0 + (size_t)m * 2048;
            u32 g[8];
            #pragma unroll
            for (int j = 0; j < 8; ++j) g[j] = cpk[lab[(8 * c + j) * 128 + n]];
            v4u lo, hi;
            #pragma unroll
            for (int r = 0; r < 4; ++r) {
                lo[r] = PLO(g[2 * r + 1], g[2 * r]);
                hi[r] = PHI(g[2 * r + 1], g[2 * r]);
            }
            u16* b0 = w0pl + (size_t)m * 4096;
            *(v4u*)(b0 + c * 1024 + n * 8)        = lo;
            *(v4u*)(b0 + 2048 + c * 1024 + n * 8) = hi;
        } else if (t < 384) {
            const int kk = t - 256;
            const u32 u = cpk[256 + lab3[(size_t)m * 128 + kk]];
            w3pl[(size_t)m * 256 + kk]       = (u16)u;
            w3pl[(size_t)m * 256 + 128 + kk] = (u16)(u >> 16);
        }
    }
}

// ---------------------------------------------------------------------------
// K2: fused forward. LDS: Hlo/Hhi 2x16896 + biasS 1536 + red 1024 = 36352 B.
// ---------------------------------------------------------------------------
__global__ __launch_bounds__(512, 8)
void ecnr_fwd(const float* __restrict__ x,
              const int*   __restrict__ mlp_idx,
              const int*   __restrict__ block_idx,
              const float* __restrict__ latent,
              const float* __restrict__ bias0, const float* __restrict__ bias1,
              const float* __restrict__ bias2, const float* __restrict__ bias3,
              const u16* __restrict__ wpl1, const u16* __restrict__ wpl2,
              const u16* __restrict__ w0pl, const u16* __restrict__ w3pl,
              float* __restrict__ out)
{
    __shared__ __attribute__((aligned(16))) u16   Hlo[64 * 132];
    __shared__ __attribute__((aligned(16))) u16   Hhi[64 * 132];
    __shared__ __attribute__((aligned(16))) float biasS[3 * 128];
    __shared__ __attribute__((aligned(16))) float red[2 * 128];

    const int t  = threadIdx.x;
    const int b  = blockIdx.x & 255;        // sample-major -> XCD locality
    const int p0 = (blockIdx.x >> 8) * 64;
    const int m  = mlp_idx[b];

    const int l  = t & 63, w = t >> 6;
    const int q  = l >> 5, ln = l & 31;
    const int pt = w & 1, nt = w >> 1;      // 2 pt x 4 nt tiles of 32x32
    const int mrow = pt * 32 + ln;          // point row (B operand / H row)
    const int nn   = nt * 32 + ln;          // channel (A operand / W row)

    // ---- stage scaled-nothing biases; issue global loads ----
    if (t < 128) {
        biasS[t]       = bias0[m * 128 + t];
        biasS[128 + t] = bias1[m * 128 + t];
        biasS[256 + t] = bias2[m * 128 + t];
    }
    const float* xp = x + (size_t)(b * 2048 + p0 + mrow) * 3;
    const float xv0 = xp[0], xv1 = xp[1], xv2 = xp[2];
    const u16* w0p = w0pl + (size_t)m * 4096 + q * 1024 + nn * 8;
    const v4u w0lo = *(const v4u*)(w0p);
    const v4u w0hi = *(const v4u*)(w0p + 2048);
    const float* zp = latent + ((size_t)m * 8 + block_idx[b]) * 13;
    float zr[8];
    #pragma unroll
    for (int j = 0; j < 8; ++j) zr[j] = zp[q * 5 + j];
    __syncthreads();  // B0: biasS visible

    // epilogue write bases (4 consecutive n per group, 8 n between groups)
    u16* lop = Hlo + mrow * 132 + nt * 32 + 4 * q;
    u16* hip = Hhi + mrow * 132 + nt * 32 + 4 * q;
    const int bidx = nt * 32 + 4 * q;       // bias frag base index

    // ---- layer 0: A = W0 (regs), B = input^T (regs) ----
    {
        float fin[8];
        if (q == 0) {
            fin[0] = xv0; fin[1] = xv1; fin[2] = xv2;
            #pragma unroll
            for (int j = 0; j < 5; ++j) fin[3 + j] = zr[j];
        } else {
            #pragma unroll
            for (int j = 0; j < 8; ++j) fin[j] = zr[j];
        }
        u32 lu[8], hu[8];
        #pragma unroll
        for (int j = 0; j < 8; ++j) {
            const __bf16 bl = (__bf16)fin[j];
            lu[j] = (u32)__builtin_bit_cast(u16, bl);
            const __bf16 bh = (__bf16)(fin[j] - (float)bl);
            hu[j] = (u32)__builtin_bit_cast(u16, bh);
        }
        v4u il, ih;
        #pragma unroll
        for (int r = 0; r < 4; ++r) {
            il[r] = PLO(lu[2 * r + 1], lu[2 * r]);
            ih[r] = PLO(hu[2 * r + 1], hu[2 * r]);
        }
        const v8bf inlo = __builtin_bit_cast(v8bf, il);
        const v8bf inhi = __builtin_bit_cast(v8bf, ih);
        const v8bf wl = __builtin_bit_cast(v8bf, w0lo);
        const v8bf wh = __builtin_bit_cast(v8bf, w0hi);
        v16f acc;
        #pragma unroll
        for (int g = 0; g < 4; ++g) {
            const float4 bv = *(const float4*)&biasS[bidx + 8 * g];
            acc[4 * g] = bv.x; acc[4 * g + 1] = bv.y;
            acc[4 * g + 2] = bv.z; acc[4 * g + 3] = bv.w;
        }
        acc = MFMA(wl, inlo, acc);
        acc = MFMA(wl, inhi, acc);
        acc = MFMA(wh, inlo, acc);
        acc = MFMA(wh, inhi, acc);
        #pragma unroll
        for (int g = 0; g < 4; ++g) {
            u32 lo2[4], hi2[4];
            #pragma unroll
            for (int e = 0; e < 4; ++e) {
                const float s = sin_omega(acc[4 * g + e]);
                const __bf16 bl = (__bf16)s;
                lo2[e] = (u32)__builtin_bit_cast(u16, bl);
                const __bf16 bh = (__bf16)(s - (float)bl);
                hi2[e] = (u32)__builtin_bit_cast(u16, bh);
            }
            v2u lov, hiv;
            lov[0] = PLO(lo2[1], lo2[0]); lov[1] = PLO(lo2[3], lo2[2]);
            hiv[0] = PLO(hi2[1], hi2[0]); hiv[1] = PLO(hi2[3], hi2[2]);
            *(v2u*)(lop + 8 * g) = lov;
            *(v2u*)(hip + 8 * g) = hiv;
        }
    }
    __syncthreads();  // B1: H(L0) visible

    // ---- layers 1,2: A = W (global b128), B = H^T (LDS b128, no unpack) ----
    const u16* HLO = Hlo + mrow * 132 + q * 8;
    const u16* HHI = Hhi + mrow * 132 + q * 8;
    #pragma unroll 1
    for (int L = 0; L < 2; ++L) {
        const u16* Wb = (L ? wpl2 : wpl1) + (size_t)m * 32768 + q * 1024 + nn * 8;
        v16f acc;
        #pragma unroll
        for (int g = 0; g < 4; ++g) {
            const float4 bv = *(const float4*)&biasS[(L + 1) * 128 + bidx + 8 * g];
            acc[4 * g] = bv.x; acc[4 * g + 1] = bv.y;
            acc[4 * g + 2] = bv.z; acc[4 * g + 3] = bv.w;
        }
        #pragma unroll
        for (int kc = 0; kc < 8; ++kc) {
            const v8bf wlo = *(const v8bf*)(Wb + kc * 2048);
            const v8bf whi = *(const v8bf*)(Wb + kc * 2048 + 16384);
            const v8bf hlo = *(const v8bf*)(HLO + kc * 16);
            const v8bf hhi = *(const v8bf*)(HHI + kc * 16);
            acc = MFMA(wlo, hlo, acc);
            acc = MFMA(wlo, hhi, acc);
            acc = MFMA(whi, hlo, acc);
            acc = MFMA(whi, hhi, acc);
        }
        __syncthreads();  // B2/B4: all H reads of this layer done
        #pragma unroll
        for (int g = 0; g < 4; ++g) {
            u32 lo2[4], hi2[4];
            #pragma unroll
            for (int e = 0; e < 4; ++e) {
                const float s = sin_omega(acc[4 * g + e]);
                const __bf16 bl = (__bf16)s;
                lo2[e] = (u32)__builtin_bit_cast(u16, bl);
                const __bf16 bh = (__bf16)(s - (float)bl);
                hi2[e] = (u32)__builtin_bit_cast(u16, bh);
            }
            v2u lov, hiv;
            lov[0] = PLO(lo2[1], lo2[0]); lov[1] = PLO(lo2[3], lo2[2]);
            hiv[0] = PLO(hi2[1], hi2[0]); hiv[1] = PLO(hi2[3], hi2[2]);
            *(v2u*)(lop + 8 * g) = lov;
            *(v2u*)(hip + 8 * g) = hiv;
        }
        __syncthreads();  // B3/B5: H(L) visible
    }

    // ---- layer 3 on MFMA: A = w3 (broadcast), B = H^T; k-split by nt ----
    {
        const u16* w3b = w3pl + (size_t)m * 256 + nt * 32 + q * 8;
        const u16* h3l = Hlo + mrow * 132 + nt * 32 + q * 8;
        const u16* h3h = Hhi + mrow * 132 + nt * 32 + q * 8;
        v16f a3;
        #pragma unroll
        for (int r = 0; r < 16; ++r) a3[r] = 0.0f;
        #pragma unroll
        for (int kc = 0; kc < 2; ++kc) {
            const v8bf wl = *(const v8bf*)(w3b + kc * 16);
            const v8bf wh = *(const v8bf*)(w3b + 128 + kc * 16);
            const v8bf hl = *(const v8bf*)(h3l + kc * 16);
            const v8bf hh = *(const v8bf*)(h3h + kc * 16);
            a3 = MFMA(wl, hl, a3);
            a3 = MFMA(wl, hh, a3);
            a3 = MFMA(wh, hl, a3);
        }
        if (q == 0) red[pt * 128 + nt * 32 + ln] = a3[0];
    }
    __syncthreads();  // B6

    if (t < 64) {
        const int rp = (t >> 5) * 128, rl = t & 31;
        const float o = bias3[m]
            + red[rp + rl] + red[rp + 32 + rl]
            + red[rp + 64 + rl] + red[rp + 96 + rl];
        out[(size_t)b * 2048 + p0 + t] = o;
    }
}

extern "C" void kernel_launch(void* const* d_in, const int* in_sizes, int n_in,
                              void* d_out, int out_size, void* d_ws, size_t ws_size,
                              hipStream_t stream) {
    (void)in_sizes; (void)n_in; (void)out_size; (void)ws_size;
    u16* wpl1 = (u16*)d_ws;                        // 16 MB
    u16* wpl2 = wpl1 + (size_t)256 * 32768;        // 16 MB
    u16* w0pl = wpl2 + (size_t)256 * 32768;        // 2 MB
    u16* w3pl = w0pl + (size_t)256 * 4096;         // 128 KB

    ecnr_dequant<<<768, 512, 0, stream>>>(
        (const float*)d_in[4],  (const int*)d_in[5],
        (const float*)d_in[7],  (const int*)d_in[8],
        (const float*)d_in[10], (const int*)d_in[11],
        (const float*)d_in[13], (const int*)d_in[14],
        wpl1, wpl2, w0pl, w3pl);

    ecnr_fwd<<<8192, 512, 0, stream>>>(
        (const float*)d_in[0], (const int*)d_in[1], (const int*)d_in[2],
        (const float*)d_in[3],
        (const float*)d_in[6], (const float*)d_in[9],
        (const float*)d_in[12], (const float*)d_in[15],
        wpl1, wpl2, w0pl, w3pl,
        (float*)d_out);
}

// Round 9
// 272.021 us; speedup vs baseline: 1.4596x; 1.4596x over previous
//
#include <hip/hip_runtime.h>

// ECNR forward, R9 = R8 with ONE fix: H planes stride 132 -> 136 u16 so every
// hot ds_read_b128 / ds_write_b64 row base is 16B-aligned (272 B = 17*16).
// R8's u16-stride-132 rows were 8-mod-16 -> compiler split the wide LDS ops,
// which caused the R8 stall regression (all pipes <30% at 86% occupancy).
//  K1 ecnr_dequant: unchanged from R8.
//  K2 ecnr_fwd: 8192 x 512 (8 waves, 4 blocks/CU). A = W (global b128),
//     B = H^T (LDS b128 pre-split lo/hi planes, zero unpack VALU).
//     Epilogue ds_write_b64 groups. L3 on MFMA. 7 barriers.

typedef unsigned int u32;
typedef unsigned short u16;
typedef __bf16 v8bf  __attribute__((ext_vector_type(8)));
typedef float  v16f  __attribute__((ext_vector_type(16)));
typedef u32    v4u   __attribute__((ext_vector_type(4)));
typedef u32    v2u   __attribute__((ext_vector_type(2)));

#define MFMA(a, b, c) __builtin_amdgcn_mfma_f32_32x32x16_bf16(a, b, c, 0, 0, 0)

#define HSTRIDE 136   // u16; 272 B rows: 16B-aligned, bank-balanced (68 dw == 4 mod 32)

// sin(30*pre) = v_sin(v_fract(pre * 30/2pi)) — same math as r5-r8.
__device__ __forceinline__ float sin_omega(float pre) {
    float rev = pre * 4.774648292756860f;
    return __builtin_amdgcn_sinf(__builtin_amdgcn_fractf(rev));
}

// fp32 -> packed bf16x2 (low16 = rne leading split, high16 = residual)
__device__ __forceinline__ u32 pack2(float c) {
    __bf16 b0 = (__bf16)c;
    float  f0 = (float)b0;
    __bf16 b1 = (__bf16)(c - f0);
    return (u32)__builtin_bit_cast(u16, b0) |
           ((u32)__builtin_bit_cast(u16, b1) << 16);
}

#define PLO(a, b) __builtin_amdgcn_perm((a), (b), 0x05040100u)  // b.lo16 | a.lo16<<16
#define PHI(a, b) __builtin_amdgcn_perm((a), (b), 0x07060302u)  // b.hi16 | a.hi16<<16

// ---------------------------------------------------------------------------
// K1: dequant (unchanged from R8). blocks 0..511: (m=blk>>1, L=blk&1) full
// 128x128 layer -> lo|hi planes, element (n,k) at (k>>3)*1024 + n*8 + (k&7)
// u16 (hi +16384). blocks 512..767: W0 planes + w3 (lo[128]|hi[128]).
// ---------------------------------------------------------------------------
__global__ __launch_bounds__(512)
void ecnr_dequant(const float* __restrict__ cent0, const int* __restrict__ lab0,
                  const float* __restrict__ cent1, const int* __restrict__ lab1,
                  const float* __restrict__ cent2, const int* __restrict__ lab2,
                  const float* __restrict__ cent3, const int* __restrict__ lab3,
                  u16* __restrict__ wpl1, u16* __restrict__ wpl2,
                  u16* __restrict__ w0pl, u16* __restrict__ w3pl)
{
    __shared__ u32 cpk[512];
    const int t = threadIdx.x;

    if (blockIdx.x < 512) {
        const int m = blockIdx.x >> 1, L = blockIdx.x & 1;
        if (t < 256) cpk[t] = pack2((L ? cent2 : cent1)[t]);
        __syncthreads();
        const int* lab = (L ? lab2 : lab1) + (size_t)m * 16384;
        u16* base = (L ? wpl2 : wpl1) + (size_t)m * 32768;
        #pragma unroll
        for (int i = 0; i < 4; ++i) {
            const int id = i * 512 + t;
            const int n = id & 127, c = id >> 7;
            u32 g[8];
            #pragma unroll
            for (int j = 0; j < 8; ++j) g[j] = cpk[lab[(8 * c + j) * 128 + n]];
            v4u lo, hi;
            #pragma unroll
            for (int r = 0; r < 4; ++r) {
                lo[r] = PLO(g[2 * r + 1], g[2 * r]);
                hi[r] = PHI(g[2 * r + 1], g[2 * r]);
            }
            *(v4u*)(base + c * 1024 + n * 8)         = lo;
            *(v4u*)(base + 16384 + c * 1024 + n * 8) = hi;
        }
    } else {
        const int m = blockIdx.x - 512;
        if (t < 256) cpk[t] = pack2(cent0[t]);
        else         cpk[t] = pack2(cent3[t - 256]);
        __syncthreads();
        if (t < 256) {
            const int n = t & 127, c = t >> 7;
            const int* lab = lab0 + (size_t)m * 2048;
            u32 g[8];
            #pragma unroll
            for (int j = 0; j < 8; ++j) g[j] = cpk[lab[(8 * c + j) * 128 + n]];
            v4u lo, hi;
            #pragma unroll
            for (int r = 0; r < 4; ++r) {
                lo[r] = PLO(g[2 * r + 1], g[2 * r]);
                hi[r] = PHI(g[2 * r + 1], g[2 * r]);
            }
            u16* b0 = w0pl + (size_t)m * 4096;
            *(v4u*)(b0 + c * 1024 + n * 8)        = lo;
            *(v4u*)(b0 + 2048 + c * 1024 + n * 8) = hi;
        } else if (t < 384) {
            const int kk = t - 256;
            const u32 u = cpk[256 + lab3[(size_t)m * 128 + kk]];
            w3pl[(size_t)m * 256 + kk]       = (u16)u;
            w3pl[(size_t)m * 256 + 128 + kk] = (u16)(u >> 16);
        }
    }
}

// ---------------------------------------------------------------------------
// K2: fused forward. LDS: Hlo/Hhi 2x17408 + biasS 1536 + red 1024 = 37376 B
// -> 4 blocks/CU (32 waves).
// ---------------------------------------------------------------------------
__global__ __launch_bounds__(512, 8)
void ecnr_fwd(const float* __restrict__ x,
              const int*   __restrict__ mlp_idx,
              const int*   __restrict__ block_idx,
              const float* __restrict__ latent,
              const float* __restrict__ bias0, const float* __restrict__ bias1,
              const float* __restrict__ bias2, const float* __restrict__ bias3,
              const u16* __restrict__ wpl1, const u16* __restrict__ wpl2,
              const u16* __restrict__ w0pl, const u16* __restrict__ w3pl,
              float* __restrict__ out)
{
    __shared__ __attribute__((aligned(16))) u16   Hlo[64 * HSTRIDE];
    __shared__ __attribute__((aligned(16))) u16   Hhi[64 * HSTRIDE];
    __shared__ __attribute__((aligned(16))) float biasS[3 * 128];
    __shared__ __attribute__((aligned(16))) float red[2 * 128];

    const int t  = threadIdx.x;
    const int b  = blockIdx.x & 255;        // sample-major -> XCD locality
    const int p0 = (blockIdx.x >> 8) * 64;
    const int m  = mlp_idx[b];

    const int l  = t & 63, w = t >> 6;
    const int q  = l >> 5, ln = l & 31;
    const int pt = w & 1, nt = w >> 1;      // 2 pt x 4 nt tiles of 32x32
    const int mrow = pt * 32 + ln;          // point row (B operand / H row)
    const int nn   = nt * 32 + ln;          // channel (A operand / W row)

    // ---- stage biases; issue global loads ----
    if (t < 128) {
        biasS[t]       = bias0[m * 128 + t];
        biasS[128 + t] = bias1[m * 128 + t];
        biasS[256 + t] = bias2[m * 128 + t];
    }
    const float* xp = x + (size_t)(b * 2048 + p0 + mrow) * 3;
    const float xv0 = xp[0], xv1 = xp[1], xv2 = xp[2];
    const u16* w0p = w0pl + (size_t)m * 4096 + q * 1024 + nn * 8;
    const v4u w0lo = *(const v4u*)(w0p);
    const v4u w0hi = *(const v4u*)(w0p + 2048);
    const float* zp = latent + ((size_t)m * 8 + block_idx[b]) * 13;
    float zr[8];
    #pragma unroll
    for (int j = 0; j < 8; ++j) zr[j] = zp[q * 5 + j];
    __syncthreads();  // B0: biasS visible

    // epilogue write bases (4 consecutive n per group, 8 n between groups)
    u16* lop = Hlo + mrow * HSTRIDE + nt * 32 + 4 * q;
    u16* hip = Hhi + mrow * HSTRIDE + nt * 32 + 4 * q;
    const int bidx = nt * 32 + 4 * q;       // bias frag base index

    // ---- layer 0: A = W0 (regs), B = input^T (regs) ----
    {
        float fin[8];
        if (q == 0) {
            fin[0] = xv0; fin[1] = xv1; fin[2] = xv2;
            #pragma unroll
            for (int j = 0; j < 5; ++j) fin[3 + j] = zr[j];
        } else {
            #pragma unroll
            for (int j = 0; j < 8; ++j) fin[j] = zr[j];
        }
        u32 lu[8], hu[8];
        #pragma unroll
        for (int j = 0; j < 8; ++j) {
            const __bf16 bl = (__bf16)fin[j];
            lu[j] = (u32)__builtin_bit_cast(u16, bl);
            const __bf16 bh = (__bf16)(fin[j] - (float)bl);
            hu[j] = (u32)__builtin_bit_cast(u16, bh);
        }
        v4u il, ih;
        #pragma unroll
        for (int r = 0; r < 4; ++r) {
            il[r] = PLO(lu[2 * r + 1], lu[2 * r]);
            ih[r] = PLO(hu[2 * r + 1], hu[2 * r]);
        }
        const v8bf inlo = __builtin_bit_cast(v8bf, il);
        const v8bf inhi = __builtin_bit_cast(v8bf, ih);
        const v8bf wl = __builtin_bit_cast(v8bf, w0lo);
        const v8bf wh = __builtin_bit_cast(v8bf, w0hi);
        v16f acc;
        #pragma unroll
        for (int g = 0; g < 4; ++g) {
            const float4 bv = *(const float4*)&biasS[bidx + 8 * g];
            acc[4 * g] = bv.x; acc[4 * g + 1] = bv.y;
            acc[4 * g + 2] = bv.z; acc[4 * g + 3] = bv.w;
        }
        acc = MFMA(wl, inlo, acc);
        acc = MFMA(wl, inhi, acc);
        acc = MFMA(wh, inlo, acc);
        acc = MFMA(wh, inhi, acc);
        #pragma unroll
        for (int g = 0; g < 4; ++g) {
            u32 lo2[4], hi2[4];
            #pragma unroll
            for (int e = 0; e < 4; ++e) {
                const float s = sin_omega(acc[4 * g + e]);
                const __bf16 bl = (__bf16)s;
                lo2[e] = (u32)__builtin_bit_cast(u16, bl);
                const __bf16 bh = (__bf16)(s - (float)bl);
                hi2[e] = (u32)__builtin_bit_cast(u16, bh);
            }
            v2u lov, hiv;
            lov[0] = PLO(lo2[1], lo2[0]); lov[1] = PLO(lo2[3], lo2[2]);
            hiv[0] = PLO(hi2[1], hi2[0]); hiv[1] = PLO(hi2[3], hi2[2]);
            *(v2u*)(lop + 8 * g) = lov;
            *(v2u*)(hip + 8 * g) = hiv;
        }
    }
    __syncthreads();  // B1: H(L0) visible

    // ---- layers 1,2: A = W (global b128), B = H^T (LDS b128, no unpack) ----
    const u16* HLO = Hlo + mrow * HSTRIDE + q * 8;
    const u16* HHI = Hhi + mrow * HSTRIDE + q * 8;
    #pragma unroll 1
    for (int L = 0; L < 2; ++L) {
        const u16* Wb = (L ? wpl2 : wpl1) + (size_t)m * 32768 + q * 1024 + nn * 8;
        v16f acc;
        #pragma unroll
        for (int g = 0; g < 4; ++g) {
            const float4 bv = *(const float4*)&biasS[(L + 1) * 128 + bidx + 8 * g];
            acc[4 * g] = bv.x; acc[4 * g + 1] = bv.y;
            acc[4 * g + 2] = bv.z; acc[4 * g + 3] = bv.w;
        }
        #pragma unroll
        for (int kc = 0; kc < 8; ++kc) {
            const v8bf wlo = *(const v8bf*)(Wb + kc * 2048);
            const v8bf whi = *(const v8bf*)(Wb + kc * 2048 + 16384);
            const v8bf hlo = *(const v8bf*)(HLO + kc * 16);
            const v8bf hhi = *(const v8bf*)(HHI + kc * 16);
            acc = MFMA(wlo, hlo, acc);
            acc = MFMA(wlo, hhi, acc);
            acc = MFMA(whi, hlo, acc);
            acc = MFMA(whi, hhi, acc);
        }
        __syncthreads();  // B2/B4: all H reads of this layer done
        #pragma unroll
        for (int g = 0; g < 4; ++g) {
            u32 lo2[4], hi2[4];
            #pragma unroll
            for (int e = 0; e < 4; ++e) {
                const float s = sin_omega(acc[4 * g + e]);
                const __bf16 bl = (__bf16)s;
                lo2[e] = (u32)__builtin_bit_cast(u16, bl);
                const __bf16 bh = (__bf16)(s - (float)bl);
                hi2[e] = (u32)__builtin_bit_cast(u16, bh);
            }
            v2u lov, hiv;
            lov[0] = PLO(lo2[1], lo2[0]); lov[1] = PLO(lo2[3], lo2[2]);
            hiv[0] = PLO(hi2[1], hi2[0]); hiv[1] = PLO(hi2[3], hi2[2]);
            *(v2u*)(lop + 8 * g) = lov;
            *(v2u*)(hip + 8 * g) = hiv;
        }
        __syncthreads();  // B3/B5: H(L) visible
    }

    // ---- layer 3 on MFMA: A = w3 (broadcast), B = H^T; k-split by nt ----
    {
        const u16* w3b = w3pl + (size_t)m * 256 + nt * 32 + q * 8;
        const u16* h3l = Hlo + mrow * HSTRIDE + nt * 32 + q * 8;
        const u16* h3h = Hhi + mrow * HSTRIDE + nt * 32 + q * 8;
        v16f a3;
        #pragma unroll
        for (int r = 0; r < 16; ++r) a3[r] = 0.0f;
        #pragma unroll
        for (int kc = 0; kc < 2; ++kc) {
            const v8bf wl = *(const v8bf*)(w3b + kc * 16);
            const v8bf wh = *(const v8bf*)(w3b + 128 + kc * 16);
            const v8bf hl = *(const v8bf*)(h3l + kc * 16);
            const v8bf hh = *(const v8bf*)(h3h + kc * 16);
            a3 = MFMA(wl, hl, a3);
            a3 = MFMA(wl, hh, a3);
            a3 = MFMA(wh, hl, a3);
        }
        if (q == 0) red[pt * 128 + nt * 32 + ln] = a3[0];
    }
    __syncthreads();  // B6

    if (t < 64) {
        const int rp = (t >> 5) * 128, rl = t & 31;
        const float o = bias3[m]
            + red[rp + rl] + red[rp + 32 + rl]
            + red[rp + 64 + rl] + red[rp + 96 + rl];
        out[(size_t)b * 2048 + p0 + t] = o;
    }
}

extern "C" void kernel_launch(void* const* d_in, const int* in_sizes, int n_in,
                              void* d_out, int out_size, void* d_ws, size_t ws_size,
                              hipStream_t stream) {
    (void)in_sizes; (void)n_in; (void)out_size; (void)ws_size;
    u16* wpl1 = (u16*)d_ws;                        // 16 MB
    u16* wpl2 = wpl1 + (size_t)256 * 32768;        // 16 MB
    u16* w0pl = wpl2 + (size_t)256 * 32768;        // 2 MB
    u16* w3pl = w0pl + (size_t)256 * 4096;         // 128 KB

    ecnr_dequant<<<768, 512, 0, stream>>>(
        (const float*)d_in[4],  (const int*)d_in[5],
        (const float*)d_in[7],  (const int*)d_in[8],
        (const float*)d_in[10], (const int*)d_in[11],
        (const float*)d_in[13], (const int*)d_in[14],
        wpl1, wpl2, w0pl, w3pl);

    ecnr_fwd<<<8192, 512, 0, stream>>>(
        (const float*)d_in[0], (const int*)d_in[1], (const int*)d_in[2],
        (const float*)d_in[3],
        (const float*)d_in[6], (const float*)d_in[9],
        (const float*)d_in[12], (const float*)d_in[15],
        wpl1, wpl2, w0pl, w3pl,
        (float*)d_out);
}

// Round 10
// 262.608 us; speedup vs baseline: 1.5119x; 1.0358x over previous
//
#include <hip/hip_runtime.h>

// ECNR forward, R10 = R9 with:
//  (a) 3 MFMA products in L0/L1/L2 (drop residual*residual whi*hhi; R4-proven
//      accuracy point, absmax ~0.0273 vs threshold 0.0395). MFMA cyc -25%.
//  (b) B0 barrier deleted: L0 bias loaded global->reg; biasS holds only
//      L1/L2 biases, visibility ordered by B1.
//  K1 ecnr_dequant unchanged (pre-split lo/hi chunk-major planes).
//  K2: 8192 x 512 (8 waves, 4 blocks/CU, 37 KB LDS), A=W (global b128),
//      B=H^T (LDS b128, 16B-aligned stride-136 rows), L3 on MFMA.

typedef unsigned int u32;
typedef unsigned short u16;
typedef __bf16 v8bf  __attribute__((ext_vector_type(8)));
typedef float  v16f  __attribute__((ext_vector_type(16)));
typedef u32    v4u   __attribute__((ext_vector_type(4)));
typedef u32    v2u   __attribute__((ext_vector_type(2)));

#define MFMA(a, b, c) __builtin_amdgcn_mfma_f32_32x32x16_bf16(a, b, c, 0, 0, 0)

#define HSTRIDE 136   // u16; 272 B rows: 16B-aligned, bank-balanced

// sin(30*pre) = v_sin(v_fract(pre * 30/2pi))
__device__ __forceinline__ float sin_omega(float pre) {
    float rev = pre * 4.774648292756860f;
    return __builtin_amdgcn_sinf(__builtin_amdgcn_fractf(rev));
}

// fp32 -> packed bf16x2 (low16 = rne leading split, high16 = residual)
__device__ __forceinline__ u32 pack2(float c) {
    __bf16 b0 = (__bf16)c;
    float  f0 = (float)b0;
    __bf16 b1 = (__bf16)(c - f0);
    return (u32)__builtin_bit_cast(u16, b0) |
           ((u32)__builtin_bit_cast(u16, b1) << 16);
}

#define PLO(a, b) __builtin_amdgcn_perm((a), (b), 0x05040100u)
#define PHI(a, b) __builtin_amdgcn_perm((a), (b), 0x07060302u)

// ---------------------------------------------------------------------------
// K1: dequant (unchanged from R8/R9).
// ---------------------------------------------------------------------------
__global__ __launch_bounds__(512)
void ecnr_dequant(const float* __restrict__ cent0, const int* __restrict__ lab0,
                  const float* __restrict__ cent1, const int* __restrict__ lab1,
                  const float* __restrict__ cent2, const int* __restrict__ lab2,
                  const float* __restrict__ cent3, const int* __restrict__ lab3,
                  u16* __restrict__ wpl1, u16* __restrict__ wpl2,
                  u16* __restrict__ w0pl, u16* __restrict__ w3pl)
{
    __shared__ u32 cpk[512];
    const int t = threadIdx.x;

    if (blockIdx.x < 512) {
        const int m = blockIdx.x >> 1, L = blockIdx.x & 1;
        if (t < 256) cpk[t] = pack2((L ? cent2 : cent1)[t]);
        __syncthreads();
        const int* lab = (L ? lab2 : lab1) + (size_t)m * 16384;
        u16* base = (L ? wpl2 : wpl1) + (size_t)m * 32768;
        #pragma unroll
        for (int i = 0; i < 4; ++i) {
            const int id = i * 512 + t;
            const int n = id & 127, c = id >> 7;
            u32 g[8];
            #pragma unroll
            for (int j = 0; j < 8; ++j) g[j] = cpk[lab[(8 * c + j) * 128 + n]];
            v4u lo, hi;
            #pragma unroll
            for (int r = 0; r < 4; ++r) {
                lo[r] = PLO(g[2 * r + 1], g[2 * r]);
                hi[r] = PHI(g[2 * r + 1], g[2 * r]);
            }
            *(v4u*)(base + c * 1024 + n * 8)         = lo;
            *(v4u*)(base + 16384 + c * 1024 + n * 8) = hi;
        }
    } else {
        const int m = blockIdx.x - 512;
        if (t < 256) cpk[t] = pack2(cent0[t]);
        else         cpk[t] = pack2(cent3[t - 256]);
        __syncthreads();
        if (t < 256) {
            const int n = t & 127, c = t >> 7;
            const int* lab = lab0 + (size_t)m * 2048;
            u32 g[8];
            #pragma unroll
            for (int j = 0; j < 8; ++j) g[j] = cpk[lab[(8 * c + j) * 128 + n]];
            v4u lo, hi;
            #pragma unroll
            for (int r = 0; r < 4; ++r) {
                lo[r] = PLO(g[2 * r + 1], g[2 * r]);
                hi[r] = PHI(g[2 * r + 1], g[2 * r]);
            }
            u16* b0 = w0pl + (size_t)m * 4096;
            *(v4u*)(b0 + c * 1024 + n * 8)        = lo;
            *(v4u*)(b0 + 2048 + c * 1024 + n * 8) = hi;
        } else if (t < 384) {
            const int kk = t - 256;
            const u32 u = cpk[256 + lab3[(size_t)m * 128 + kk]];
            w3pl[(size_t)m * 256 + kk]       = (u16)u;
            w3pl[(size_t)m * 256 + 128 + kk] = (u16)(u >> 16);
        }
    }
}

// ---------------------------------------------------------------------------
// K2: fused forward. LDS: Hlo/Hhi 2x17408 + biasS 1024 + red 1024 = 36864 B.
// ---------------------------------------------------------------------------
__global__ __launch_bounds__(512, 8)
void ecnr_fwd(const float* __restrict__ x,
              const int*   __restrict__ mlp_idx,
              const int*   __restrict__ block_idx,
              const float* __restrict__ latent,
              const float* __restrict__ bias0, const float* __restrict__ bias1,
              const float* __restrict__ bias2, const float* __restrict__ bias3,
              const u16* __restrict__ wpl1, const u16* __restrict__ wpl2,
              const u16* __restrict__ w0pl, const u16* __restrict__ w3pl,
              float* __restrict__ out)
{
    __shared__ __attribute__((aligned(16))) u16   Hlo[64 * HSTRIDE];
    __shared__ __attribute__((aligned(16))) u16   Hhi[64 * HSTRIDE];
    __shared__ __attribute__((aligned(16))) float biasS[2 * 128];
    __shared__ __attribute__((aligned(16))) float red[2 * 128];

    const int t  = threadIdx.x;
    const int b  = blockIdx.x & 255;        // sample-major -> XCD locality
    const int p0 = (blockIdx.x >> 8) * 64;
    const int m  = mlp_idx[b];

    const int l  = t & 63, w = t >> 6;
    const int q  = l >> 5, ln = l & 31;
    const int pt = w & 1, nt = w >> 1;      // 2 pt x 4 nt tiles of 32x32
    const int mrow = pt * 32 + ln;          // point row (B operand / H row)
    const int nn   = nt * 32 + ln;          // channel (A operand / W row)
    const int bidx = nt * 32 + 4 * q;       // bias frag base index

    // ---- stage L1/L2 biases (visibility via B1); issue global loads ----
    if (t < 128) {
        biasS[t]       = bias1[m * 128 + t];
        biasS[128 + t] = bias2[m * 128 + t];
    }
    const float* xp = x + (size_t)(b * 2048 + p0 + mrow) * 3;
    const float xv0 = xp[0], xv1 = xp[1], xv2 = xp[2];
    const u16* w0p = w0pl + (size_t)m * 4096 + q * 1024 + nn * 8;
    const v4u w0lo = *(const v4u*)(w0p);
    const v4u w0hi = *(const v4u*)(w0p + 2048);
    float4 b0f[4];
    #pragma unroll
    for (int g = 0; g < 4; ++g)
        b0f[g] = *(const float4*)(bias0 + m * 128 + bidx + 8 * g);
    const float* zp = latent + ((size_t)m * 8 + block_idx[b]) * 13;
    float zr[8];
    #pragma unroll
    for (int j = 0; j < 8; ++j) zr[j] = zp[q * 5 + j];

    // epilogue write bases (4 consecutive n per group, 8 n between groups)
    u16* lop = Hlo + mrow * HSTRIDE + nt * 32 + 4 * q;
    u16* hip = Hhi + mrow * HSTRIDE + nt * 32 + 4 * q;

    // ---- layer 0: A = W0 (regs), B = input^T (regs), 3 products ----
    {
        float fin[8];
        if (q == 0) {
            fin[0] = xv0; fin[1] = xv1; fin[2] = xv2;
            #pragma unroll
            for (int j = 0; j < 5; ++j) fin[3 + j] = zr[j];
        } else {
            #pragma unroll
            for (int j = 0; j < 8; ++j) fin[j] = zr[j];
        }
        u32 lu[8], hu[8];
        #pragma unroll
        for (int j = 0; j < 8; ++j) {
            const __bf16 bl = (__bf16)fin[j];
            lu[j] = (u32)__builtin_bit_cast(u16, bl);
            const __bf16 bh = (__bf16)(fin[j] - (float)bl);
            hu[j] = (u32)__builtin_bit_cast(u16, bh);
        }
        v4u il, ih;
        #pragma unroll
        for (int r = 0; r < 4; ++r) {
            il[r] = PLO(lu[2 * r + 1], lu[2 * r]);
            ih[r] = PLO(hu[2 * r + 1], hu[2 * r]);
        }
        const v8bf inlo = __builtin_bit_cast(v8bf, il);
        const v8bf inhi = __builtin_bit_cast(v8bf, ih);
        const v8bf wl = __builtin_bit_cast(v8bf, w0lo);
        const v8bf wh = __builtin_bit_cast(v8bf, w0hi);
        v16f acc;
        #pragma unroll
        for (int g = 0; g < 4; ++g) {
            acc[4 * g] = b0f[g].x; acc[4 * g + 1] = b0f[g].y;
            acc[4 * g + 2] = b0f[g].z; acc[4 * g + 3] = b0f[g].w;
        }
        acc = MFMA(wl, inlo, acc);
        acc = MFMA(wl, inhi, acc);
        acc = MFMA(wh, inlo, acc);
        #pragma unroll
        for (int g = 0; g < 4; ++g) {
            u32 lo2[4], hi2[4];
            #pragma unroll
            for (int e = 0; e < 4; ++e) {
                const float s = sin_omega(acc[4 * g + e]);
                const __bf16 bl = (__bf16)s;
                lo2[e] = (u32)__builtin_bit_cast(u16, bl);
                const __bf16 bh = (__bf16)(s - (float)bl);
                hi2[e] = (u32)__builtin_bit_cast(u16, bh);
            }
            v2u lov, hiv;
            lov[0] = PLO(lo2[1], lo2[0]); lov[1] = PLO(lo2[3], lo2[2]);
            hiv[0] = PLO(hi2[1], hi2[0]); hiv[1] = PLO(hi2[3], hi2[2]);
            *(v2u*)(lop + 8 * g) = lov;
            *(v2u*)(hip + 8 * g) = hiv;
        }
    }
    __syncthreads();  // B1: H(L0) + biasS visible

    // ---- layers 1,2: A = W (global b128), B = H^T (LDS b128), 3 products ----
    const u16* HLO = Hlo + mrow * HSTRIDE + q * 8;
    const u16* HHI = Hhi + mrow * HSTRIDE + q * 8;
    #pragma unroll 1
    for (int L = 0; L < 2; ++L) {
        const u16* Wb = (L ? wpl2 : wpl1) + (size_t)m * 32768 + q * 1024 + nn * 8;
        v16f acc;
        #pragma unroll
        for (int g = 0; g < 4; ++g) {
            const float4 bv = *(const float4*)&biasS[L * 128 + bidx + 8 * g];
            acc[4 * g] = bv.x; acc[4 * g + 1] = bv.y;
            acc[4 * g + 2] = bv.z; acc[4 * g + 3] = bv.w;
        }
        #pragma unroll
        for (int kc = 0; kc < 8; ++kc) {
            const v8bf wlo = *(const v8bf*)(Wb + kc * 2048);
            const v8bf whi = *(const v8bf*)(Wb + kc * 2048 + 16384);
            const v8bf hlo = *(const v8bf*)(HLO + kc * 16);
            const v8bf hhi = *(const v8bf*)(HHI + kc * 16);
            acc = MFMA(wlo, hlo, acc);
            acc = MFMA(wlo, hhi, acc);
            acc = MFMA(whi, hlo, acc);
        }
        __syncthreads();  // B2/B4: all H reads of this layer done
        #pragma unroll
        for (int g = 0; g < 4; ++g) {
            u32 lo2[4], hi2[4];
            #pragma unroll
            for (int e = 0; e < 4; ++e) {
                const float s = sin_omega(acc[4 * g + e]);
                const __bf16 bl = (__bf16)s;
                lo2[e] = (u32)__builtin_bit_cast(u16, bl);
                const __bf16 bh = (__bf16)(s - (float)bl);
                hi2[e] = (u32)__builtin_bit_cast(u16, bh);
            }
            v2u lov, hiv;
            lov[0] = PLO(lo2[1], lo2[0]); lov[1] = PLO(lo2[3], lo2[2]);
            hiv[0] = PLO(hi2[1], hi2[0]); hiv[1] = PLO(hi2[3], hi2[2]);
            *(v2u*)(lop + 8 * g) = lov;
            *(v2u*)(hip + 8 * g) = hiv;
        }
        __syncthreads();  // B3/B5: H(L) visible
    }

    // ---- layer 3 on MFMA: A = w3 (broadcast), B = H^T; k-split by nt ----
    {
        const u16* w3b = w3pl + (size_t)m * 256 + nt * 32 + q * 8;
        const u16* h3l = Hlo + mrow * HSTRIDE + nt * 32 + q * 8;
        const u16* h3h = Hhi + mrow * HSTRIDE + nt * 32 + q * 8;
        v16f a3;
        #pragma unroll
        for (int r = 0; r < 16; ++r) a3[r] = 0.0f;
        #pragma unroll
        for (int kc = 0; kc < 2; ++kc) {
            const v8bf wl = *(const v8bf*)(w3b + kc * 16);
            const v8bf wh = *(const v8bf*)(w3b + 128 + kc * 16);
            const v8bf hl = *(const v8bf*)(h3l + kc * 16);
            const v8bf hh = *(const v8bf*)(h3h + kc * 16);
            a3 = MFMA(wl, hl, a3);
            a3 = MFMA(wl, hh, a3);
            a3 = MFMA(wh, hl, a3);
        }
        if (q == 0) red[pt * 128 + nt * 32 + ln] = a3[0];
    }
    __syncthreads();  // B6

    if (t < 64) {
        const int rp = (t >> 5) * 128, rl = t & 31;
        const float o = bias3[m]
            + red[rp + rl] + red[rp + 32 + rl]
            + red[rp + 64 + rl] + red[rp + 96 + rl];
        out[(size_t)b * 2048 + p0 + t] = o;
    }
}

extern "C" void kernel_launch(void* const* d_in, const int* in_sizes, int n_in,
                              void* d_out, int out_size, void* d_ws, size_t ws_size,
                              hipStream_t stream) {
    (void)in_sizes; (void)n_in; (void)out_size; (void)ws_size;
    u16* wpl1 = (u16*)d_ws;                        // 16 MB
    u16* wpl2 = wpl1 + (size_t)256 * 32768;        // 16 MB
    u16* w0pl = wpl2 + (size_t)256 * 32768;        // 2 MB
    u16* w3pl = w0pl + (size_t)256 * 4096;         // 128 KB

    ecnr_dequant<<<768, 512, 0, stream>>>(
        (const float*)d_in[4],  (const int*)d_in[5],
        (const float*)d_in[7],  (const int*)d_in[8],
        (const float*)d_in[10], (const int*)d_in[11],
        (const float*)d_in[13], (const int*)d_in[14],
        wpl1, wpl2, w0pl, w3pl);

    ecnr_fwd<<<8192, 512, 0, stream>>>(
        (const float*)d_in[0], (const int*)d_in[1], (const int*)d_in[2],
        (const float*)d_in[3],
        (const float*)d_in[6], (const float*)d_in[9],
        (const float*)d_in[12], (const float*)d_in[15],
        wpl1, wpl2, w0pl, w3pl,
        (float*)d_out);
}

// Round 12
// 256.719 us; speedup vs baseline: 1.5466x; 1.0229x over previous
//
#include <hip/hip_runtime.h>

// ECNR forward, R12 = R11 with the swizzle FIXED (R11's covered only samples
// 0-31: it took sample-high bits from g[12:11] instead of g[12:8]).
//  (a) XCD swizzle: xcd=g&7, tile=(g>>3)&31, sample=((g>>8)<<3)|(g&7).
//      Bijective; same-sample tiles share g%8 (same XCD) and sit in one
//      256-block dispatch window -> co-resident; per-XCD W working set
//      ~4 samples x 128 KB = 512 KB << 4 MB L2 (kills R10's 3x W re-fetch).
//  (b) depth-1 register prefetch of W (lo,hi) in the kc-loop.
//  Numerics identical to R10 (bf16x2, 3 products): absmax 0.02734375.

typedef unsigned int u32;
typedef unsigned short u16;
typedef __bf16 v8bf  __attribute__((ext_vector_type(8)));
typedef float  v16f  __attribute__((ext_vector_type(16)));
typedef u32    v4u   __attribute__((ext_vector_type(4)));
typedef u32    v2u   __attribute__((ext_vector_type(2)));

#define MFMA(a, b, c) __builtin_amdgcn_mfma_f32_32x32x16_bf16(a, b, c, 0, 0, 0)

#define HSTRIDE 136   // u16; 272 B rows: 16B-aligned, bank-balanced

__device__ __forceinline__ float sin_omega(float pre) {
    float rev = pre * 4.774648292756860f;
    return __builtin_amdgcn_sinf(__builtin_amdgcn_fractf(rev));
}

__device__ __forceinline__ u32 pack2(float c) {
    __bf16 b0 = (__bf16)c;
    float  f0 = (float)b0;
    __bf16 b1 = (__bf16)(c - f0);
    return (u32)__builtin_bit_cast(u16, b0) |
           ((u32)__builtin_bit_cast(u16, b1) << 16);
}

#define PLO(a, b) __builtin_amdgcn_perm((a), (b), 0x05040100u)
#define PHI(a, b) __builtin_amdgcn_perm((a), (b), 0x07060302u)

// ---------------------------------------------------------------------------
// K1: dequant (unchanged from R8-R10).
// ---------------------------------------------------------------------------
__global__ __launch_bounds__(512)
void ecnr_dequant(const float* __restrict__ cent0, const int* __restrict__ lab0,
                  const float* __restrict__ cent1, const int* __restrict__ lab1,
                  const float* __restrict__ cent2, const int* __restrict__ lab2,
                  const float* __restrict__ cent3, const int* __restrict__ lab3,
                  u16* __restrict__ wpl1, u16* __restrict__ wpl2,
                  u16* __restrict__ w0pl, u16* __restrict__ w3pl)
{
    __shared__ u32 cpk[512];
    const int t = threadIdx.x;

    if (blockIdx.x < 512) {
        const int m = blockIdx.x >> 1, L = blockIdx.x & 1;
        if (t < 256) cpk[t] = pack2((L ? cent2 : cent1)[t]);
        __syncthreads();
        const int* lab = (L ? lab2 : lab1) + (size_t)m * 16384;
        u16* base = (L ? wpl2 : wpl1) + (size_t)m * 32768;
        #pragma unroll
        for (int i = 0; i < 4; ++i) {
            const int id = i * 512 + t;
            const int n = id & 127, c = id >> 7;
            u32 g[8];
            #pragma unroll
            for (int j = 0; j < 8; ++j) g[j] = cpk[lab[(8 * c + j) * 128 + n]];
            v4u lo, hi;
            #pragma unroll
            for (int r = 0; r < 4; ++r) {
                lo[r] = PLO(g[2 * r + 1], g[2 * r]);
                hi[r] = PHI(g[2 * r + 1], g[2 * r]);
            }
            *(v4u*)(base + c * 1024 + n * 8)         = lo;
            *(v4u*)(base + 16384 + c * 1024 + n * 8) = hi;
        }
    } else {
        const int m = blockIdx.x - 512;
        if (t < 256) cpk[t] = pack2(cent0[t]);
        else         cpk[t] = pack2(cent3[t - 256]);
        __syncthreads();
        if (t < 256) {
            const int n = t & 127, c = t >> 7;
            const int* lab = lab0 + (size_t)m * 2048;
            u32 g[8];
            #pragma unroll
            for (int j = 0; j < 8; ++j) g[j] = cpk[lab[(8 * c + j) * 128 + n]];
            v4u lo, hi;
            #pragma unroll
            for (int r = 0; r < 4; ++r) {
                lo[r] = PLO(g[2 * r + 1], g[2 * r]);
                hi[r] = PHI(g[2 * r + 1], g[2 * r]);
            }
            u16* b0 = w0pl + (size_t)m * 4096;
            *(v4u*)(b0 + c * 1024 + n * 8)        = lo;
            *(v4u*)(b0 + 2048 + c * 1024 + n * 8) = hi;
        } else if (t < 384) {
            const int kk = t - 256;
            const u32 u = cpk[256 + lab3[(size_t)m * 128 + kk]];
            w3pl[(size_t)m * 256 + kk]       = (u16)u;
            w3pl[(size_t)m * 256 + 128 + kk] = (u16)(u >> 16);
        }
    }
}

// ---------------------------------------------------------------------------
// K2: fused forward. LDS: Hlo/Hhi 2x17408 + biasS 1024 + red 1024 = 36864 B.
// ---------------------------------------------------------------------------
__global__ __launch_bounds__(512, 8)
void ecnr_fwd(const float* __restrict__ x,
              const int*   __restrict__ mlp_idx,
              const int*   __restrict__ block_idx,
              const float* __restrict__ latent,
              const float* __restrict__ bias0, const float* __restrict__ bias1,
              const float* __restrict__ bias2, const float* __restrict__ bias3,
              const u16* __restrict__ wpl1, const u16* __restrict__ wpl2,
              const u16* __restrict__ w0pl, const u16* __restrict__ w3pl,
              float* __restrict__ out)
{
    __shared__ __attribute__((aligned(16))) u16   Hlo[64 * HSTRIDE];
    __shared__ __attribute__((aligned(16))) u16   Hhi[64 * HSTRIDE];
    __shared__ __attribute__((aligned(16))) float biasS[2 * 128];
    __shared__ __attribute__((aligned(16))) float red[2 * 128];

    // XCD swizzle (bijective): xcd=g[2:0], tile=g[7:3], sample=g[12:8]<<3|xcd
    const int g    = blockIdx.x;
    const int b    = ((g >> 8) << 3) | (g & 7);    // sample 0..255
    const int p0   = ((g >> 3) & 31) * 64;         // tile * 64
    const int m    = mlp_idx[b];

    const int t  = threadIdx.x;
    const int l  = t & 63, w = t >> 6;
    const int q  = l >> 5, ln = l & 31;
    const int pt = w & 1, nt = w >> 1;      // 2 pt x 4 nt tiles of 32x32
    const int mrow = pt * 32 + ln;          // point row (B operand / H row)
    const int nn   = nt * 32 + ln;          // channel (A operand / W row)
    const int bidx = nt * 32 + 4 * q;       // bias frag base index

    // ---- stage L1/L2 biases (visibility via B1); issue global loads ----
    if (t < 128) {
        biasS[t]       = bias1[m * 128 + t];
        biasS[128 + t] = bias2[m * 128 + t];
    }
    const float* xp = x + (size_t)(b * 2048 + p0 + mrow) * 3;
    const float xv0 = xp[0], xv1 = xp[1], xv2 = xp[2];
    const u16* w0p = w0pl + (size_t)m * 4096 + q * 1024 + nn * 8;
    const v4u w0lo = *(const v4u*)(w0p);
    const v4u w0hi = *(const v4u*)(w0p + 2048);
    float4 b0f[4];
    #pragma unroll
    for (int gg = 0; gg < 4; ++gg)
        b0f[gg] = *(const float4*)(bias0 + m * 128 + bidx + 8 * gg);
    const float* zp = latent + ((size_t)m * 8 + block_idx[b]) * 13;
    float zr[8];
    #pragma unroll
    for (int j = 0; j < 8; ++j) zr[j] = zp[q * 5 + j];

    // epilogue write bases (4 consecutive n per group, 8 n between groups)
    u16* lop = Hlo + mrow * HSTRIDE + nt * 32 + 4 * q;
    u16* hip = Hhi + mrow * HSTRIDE + nt * 32 + 4 * q;

    // ---- layer 0: A = W0 (regs), B = input^T (regs), 3 products ----
    {
        float fin[8];
        if (q == 0) {
            fin[0] = xv0; fin[1] = xv1; fin[2] = xv2;
            #pragma unroll
            for (int j = 0; j < 5; ++j) fin[3 + j] = zr[j];
        } else {
            #pragma unroll
            for (int j = 0; j < 8; ++j) fin[j] = zr[j];
        }
        u32 lu[8], hu[8];
        #pragma unroll
        for (int j = 0; j < 8; ++j) {
            const __bf16 bl = (__bf16)fin[j];
            lu[j] = (u32)__builtin_bit_cast(u16, bl);
            const __bf16 bh = (__bf16)(fin[j] - (float)bl);
            hu[j] = (u32)__builtin_bit_cast(u16, bh);
        }
        v4u il, ih;
        #pragma unroll
        for (int r = 0; r < 4; ++r) {
            il[r] = PLO(lu[2 * r + 1], lu[2 * r]);
            ih[r] = PLO(hu[2 * r + 1], hu[2 * r]);
        }
        const v8bf inlo = __builtin_bit_cast(v8bf, il);
        const v8bf inhi = __builtin_bit_cast(v8bf, ih);
        const v8bf wl = __builtin_bit_cast(v8bf, w0lo);
        const v8bf wh = __builtin_bit_cast(v8bf, w0hi);
        v16f acc;
        #pragma unroll
        for (int gg = 0; gg < 4; ++gg) {
            acc[4 * gg] = b0f[gg].x; acc[4 * gg + 1] = b0f[gg].y;
            acc[4 * gg + 2] = b0f[gg].z; acc[4 * gg + 3] = b0f[gg].w;
        }
        acc = MFMA(wl, inlo, acc);
        acc = MFMA(wl, inhi, acc);
        acc = MFMA(wh, inlo, acc);
        #pragma unroll
        for (int gg = 0; gg < 4; ++gg) {
            u32 lo2[4], hi2[4];
            #pragma unroll
            for (int e = 0; e < 4; ++e) {
                const float s = sin_omega(acc[4 * gg + e]);
                const __bf16 bl = (__bf16)s;
                lo2[e] = (u32)__builtin_bit_cast(u16, bl);
                const __bf16 bh = (__bf16)(s - (float)bl);
                hi2[e] = (u32)__builtin_bit_cast(u16, bh);
            }
            v2u lov, hiv;
            lov[0] = PLO(lo2[1], lo2[0]); lov[1] = PLO(lo2[3], lo2[2]);
            hiv[0] = PLO(hi2[1], hi2[0]); hiv[1] = PLO(hi2[3], hi2[2]);
            *(v2u*)(lop + 8 * gg) = lov;
            *(v2u*)(hip + 8 * gg) = hiv;
        }
    }
    __syncthreads();  // B1: H(L0) + biasS visible

    // ---- layers 1,2: A = W (global, depth-1 reg prefetch), B = H^T (LDS) ----
    const u16* HLO = Hlo + mrow * HSTRIDE + q * 8;
    const u16* HHI = Hhi + mrow * HSTRIDE + q * 8;
    #pragma unroll 1
    for (int L = 0; L < 2; ++L) {
        const u16* Wb = (L ? wpl2 : wpl1) + (size_t)m * 32768 + q * 1024 + nn * 8;
        v16f acc;
        #pragma unroll
        for (int gg = 0; gg < 4; ++gg) {
            const float4 bv = *(const float4*)&biasS[L * 128 + bidx + 8 * gg];
            acc[4 * gg] = bv.x; acc[4 * gg + 1] = bv.y;
            acc[4 * gg + 2] = bv.z; acc[4 * gg + 3] = bv.w;
        }
        v4u wlo = *(const v4u*)(Wb);
        v4u whi = *(const v4u*)(Wb + 16384);
        #pragma unroll
        for (int kc = 0; kc < 8; ++kc) {
            v4u wlo_n, whi_n;
            if (kc < 7) {                       // prefetch next kc's W
                wlo_n = *(const v4u*)(Wb + (kc + 1) * 2048);
                whi_n = *(const v4u*)(Wb + (kc + 1) * 2048 + 16384);
            }
            const v8bf hlo = *(const v8bf*)(HLO + kc * 16);
            const v8bf hhi = *(const v8bf*)(HHI + kc * 16);
            acc = MFMA(__builtin_bit_cast(v8bf, wlo), hlo, acc);
            acc = MFMA(__builtin_bit_cast(v8bf, wlo), hhi, acc);
            acc = MFMA(__builtin_bit_cast(v8bf, whi), hlo, acc);
            wlo = wlo_n; whi = whi_n;
        }
        __syncthreads();  // B2/B4: all H reads of this layer done
        #pragma unroll
        for (int gg = 0; gg < 4; ++gg) {
            u32 lo2[4], hi2[4];
            #pragma unroll
            for (int e = 0; e < 4; ++e) {
                const float s = sin_omega(acc[4 * gg + e]);
                const __bf16 bl = (__bf16)s;
                lo2[e] = (u32)__builtin_bit_cast(u16, bl);
                const __bf16 bh = (__bf16)(s - (float)bl);
                hi2[e] = (u32)__builtin_bit_cast(u16, bh);
            }
            v2u lov, hiv;
            lov[0] = PLO(lo2[1], lo2[0]); lov[1] = PLO(lo2[3], lo2[2]);
            hiv[0] = PLO(hi2[1], hi2[0]); hiv[1] = PLO(hi2[3], hi2[2]);
            *(v2u*)(lop + 8 * gg) = lov;
            *(v2u*)(hip + 8 * gg) = hiv;
        }
        __syncthreads();  // B3/B5: H(L) visible
    }

    // ---- layer 3 on MFMA: A = w3 (broadcast), B = H^T; k-split by nt ----
    {
        const u16* w3b = w3pl + (size_t)m * 256 + nt * 32 + q * 8;
        const u16* h3l = Hlo + mrow * HSTRIDE + nt * 32 + q * 8;
        const u16* h3h = Hhi + mrow * HSTRIDE + nt * 32 + q * 8;
        v16f a3;
        #pragma unroll
        for (int r = 0; r < 16; ++r) a3[r] = 0.0f;
        #pragma unroll
        for (int kc = 0; kc < 2; ++kc) {
            const v8bf wl = *(const v8bf*)(w3b + kc * 16);
            const v8bf wh = *(const v8bf*)(w3b + 128 + kc * 16);
            const v8bf hl = *(const v8bf*)(h3l + kc * 16);
            const v8bf hh = *(const v8bf*)(h3h + kc * 16);
            a3 = MFMA(wl, hl, a3);
            a3 = MFMA(wl, hh, a3);
            a3 = MFMA(wh, hl, a3);
        }
        if (q == 0) red[pt * 128 + nt * 32 + ln] = a3[0];
    }
    __syncthreads();  // B6

    if (t < 64) {
        const int rp = (t >> 5) * 128, rl = t & 31;
        const float o = bias3[m]
            + red[rp + rl] + red[rp + 32 + rl]
            + red[rp + 64 + rl] + red[rp + 96 + rl];
        out[(size_t)b * 2048 + p0 + t] = o;
    }
}

extern "C" void kernel_launch(void* const* d_in, const int* in_sizes, int n_in,
                              void* d_out, int out_size, void* d_ws, size_t ws_size,
                              hipStream_t stream) {
    (void)in_sizes; (void)n_in; (void)out_size; (void)ws_size;
    u16* wpl1 = (u16*)d_ws;                        // 16 MB
    u16* wpl2 = wpl1 + (size_t)256 * 32768;        // 16 MB
    u16* w0pl = wpl2 + (size_t)256 * 32768;        // 2 MB
    u16* w3pl = w0pl + (size_t)256 * 4096;         // 128 KB

    ecnr_dequant<<<768, 512, 0, stream>>>(
        (const float*)d_in[4],  (const int*)d_in[5],
        (const float*)d_in[7],  (const int*)d_in[8],
        (const float*)d_in[10], (const int*)d_in[11],
        (const float*)d_in[13], (const int*)d_in[14],
        wpl1, wpl2, w0pl, w3pl);

    ecnr_fwd<<<8192, 512, 0, stream>>>(
        (const float*)d_in[0], (const int*)d_in[1], (const int*)d_in[2],
        (const float*)d_in[3],
        (const float*)d_in[6], (const float*)d_in[9],
        (const float*)d_in[12], (const float*)d_in[15],
        wpl1, wpl2, w0pl, w3pl,
        (float*)d_out);
}

// Round 14
// 245.302 us; speedup vs baseline: 1.6185x; 1.0465x over previous
//
#include <hip/hip_runtime.h>

// ECNR forward, R14 = R13 with the compile fix: pk2 writes plain u32 locals
// (vector elements can't bind to non-const refs), results assigned into
// vectors afterwards. Theory unchanged:
//  (a) explicit 3-slot register rotation, depth-2 W prefetch in the kc-loop
//      (R12's VGPR_Count=32 proved the compiler serialized W loads; ~200cyc
//      L2 latency exposed per iter vs ~96cyc of MFMA). Peak regs ~58 <= 64.
//  (b) packed bf16 converts (v_cvt_pk_bf16_f32, RNE) in epilogues + L0 split.
//  Numerics: same splits/products as R10-R12 -> absmax 0.02734375.

typedef unsigned int u32;
typedef unsigned short u16;
typedef __bf16 v8bf  __attribute__((ext_vector_type(8)));
typedef __bf16 v2bf  __attribute__((ext_vector_type(2)));
typedef float  v16f  __attribute__((ext_vector_type(16)));
typedef float  v2f   __attribute__((ext_vector_type(2)));
typedef u32    v4u   __attribute__((ext_vector_type(4)));
typedef u32    v2u   __attribute__((ext_vector_type(2)));

#define MFMA(a, b, c) __builtin_amdgcn_mfma_f32_32x32x16_bf16(a, b, c, 0, 0, 0)

#define HSTRIDE 136   // u16; 272 B rows: 16B-aligned, bank-balanced

__device__ __forceinline__ float sin_omega(float pre) {
    float rev = pre * 4.774648292756860f;
    return __builtin_amdgcn_sinf(__builtin_amdgcn_fractf(rev));
}

__device__ __forceinline__ u32 pack2(float c) {
    __bf16 b0 = (__bf16)c;
    float  f0 = (float)b0;
    __bf16 b1 = (__bf16)(c - f0);
    return (u32)__builtin_bit_cast(u16, b0) |
           ((u32)__builtin_bit_cast(u16, b1) << 16);
}

// two floats -> packed lo (bf16x2) and packed hi (residual bf16x2), RNE
__device__ __forceinline__ void pk2(float s0, float s1, u32& lo, u32& hi) {
    v2f s; s[0] = s0; s[1] = s1;
    v2bf l = __builtin_convertvector(s, v2bf);        // v_cvt_pk_bf16_f32
    u32 lov = __builtin_bit_cast(u32, l);
    v2f lf;
    lf[0] = __builtin_bit_cast(float, lov << 16);
    lf[1] = __builtin_bit_cast(float, lov & 0xffff0000u);
    v2f r = s - lf;
    v2bf h = __builtin_convertvector(r, v2bf);
    lo = lov;
    hi = __builtin_bit_cast(u32, h);
}

#define PLO(a, b) __builtin_amdgcn_perm((a), (b), 0x05040100u)
#define PHI(a, b) __builtin_amdgcn_perm((a), (b), 0x07060302u)

// ---------------------------------------------------------------------------
// K1: dequant (unchanged from R8-R12).
// ---------------------------------------------------------------------------
__global__ __launch_bounds__(512)
void ecnr_dequant(const float* __restrict__ cent0, const int* __restrict__ lab0,
                  const float* __restrict__ cent1, const int* __restrict__ lab1,
                  const float* __restrict__ cent2, const int* __restrict__ lab2,
                  const float* __restrict__ cent3, const int* __restrict__ lab3,
                  u16* __restrict__ wpl1, u16* __restrict__ wpl2,
                  u16* __restrict__ w0pl, u16* __restrict__ w3pl)
{
    __shared__ u32 cpk[512];
    const int t = threadIdx.x;

    if (blockIdx.x < 512) {
        const int m = blockIdx.x >> 1, L = blockIdx.x & 1;
        if (t < 256) cpk[t] = pack2((L ? cent2 : cent1)[t]);
        __syncthreads();
        const int* lab = (L ? lab2 : lab1) + (size_t)m * 16384;
        u16* base = (L ? wpl2 : wpl1) + (size_t)m * 32768;
        #pragma unroll
        for (int i = 0; i < 4; ++i) {
            const int id = i * 512 + t;
            const int n = id & 127, c = id >> 7;
            u32 g[8];
            #pragma unroll
            for (int j = 0; j < 8; ++j) g[j] = cpk[lab[(8 * c + j) * 128 + n]];
            v4u lo, hi;
            #pragma unroll
            for (int r = 0; r < 4; ++r) {
                lo[r] = PLO(g[2 * r + 1], g[2 * r]);
                hi[r] = PHI(g[2 * r + 1], g[2 * r]);
            }
            *(v4u*)(base + c * 1024 + n * 8)         = lo;
            *(v4u*)(base + 16384 + c * 1024 + n * 8) = hi;
        }
    } else {
        const int m = blockIdx.x - 512;
        if (t < 256) cpk[t] = pack2(cent0[t]);
        else         cpk[t] = pack2(cent3[t - 256]);
        __syncthreads();
        if (t < 256) {
            const int n = t & 127, c = t >> 7;
            const int* lab = lab0 + (size_t)m * 2048;
            u32 g[8];
            #pragma unroll
            for (int j = 0; j < 8; ++j) g[j] = cpk[lab[(8 * c + j) * 128 + n]];
            v4u lo, hi;
            #pragma unroll
            for (int r = 0; r < 4; ++r) {
                lo[r] = PLO(g[2 * r + 1], g[2 * r]);
                hi[r] = PHI(g[2 * r + 1], g[2 * r]);
            }
            u16* b0 = w0pl + (size_t)m * 4096;
            *(v4u*)(b0 + c * 1024 + n * 8)        = lo;
            *(v4u*)(b0 + 2048 + c * 1024 + n * 8) = hi;
        } else if (t < 384) {
            const int kk = t - 256;
            const u32 u = cpk[256 + lab3[(size_t)m * 128 + kk]];
            w3pl[(size_t)m * 256 + kk]       = (u16)u;
            w3pl[(size_t)m * 256 + 128 + kk] = (u16)(u >> 16);
        }
    }
}

// ---------------------------------------------------------------------------
// K2: fused forward. LDS: Hlo/Hhi 2x17408 + biasS 1024 + red 1024 = 36864 B.
// ---------------------------------------------------------------------------
__global__ __launch_bounds__(512, 8)
void ecnr_fwd(const float* __restrict__ x,
              const int*   __restrict__ mlp_idx,
              const int*   __restrict__ block_idx,
              const float* __restrict__ latent,
              const float* __restrict__ bias0, const float* __restrict__ bias1,
              const float* __restrict__ bias2, const float* __restrict__ bias3,
              const u16* __restrict__ wpl1, const u16* __restrict__ wpl2,
              const u16* __restrict__ w0pl, const u16* __restrict__ w3pl,
              float* __restrict__ out)
{
    __shared__ __attribute__((aligned(16))) u16   Hlo[64 * HSTRIDE];
    __shared__ __attribute__((aligned(16))) u16   Hhi[64 * HSTRIDE];
    __shared__ __attribute__((aligned(16))) float biasS[2 * 128];
    __shared__ __attribute__((aligned(16))) float red[2 * 128];

    // XCD swizzle (bijective): xcd=g[2:0], tile=g[7:3], sample=g[12:8]<<3|xcd
    const int g    = blockIdx.x;
    const int b    = ((g >> 8) << 3) | (g & 7);    // sample 0..255
    const int p0   = ((g >> 3) & 31) * 64;         // tile * 64
    const int m    = mlp_idx[b];

    const int t  = threadIdx.x;
    const int l  = t & 63, w = t >> 6;
    const int q  = l >> 5, ln = l & 31;
    const int pt = w & 1, nt = w >> 1;      // 2 pt x 4 nt tiles of 32x32
    const int mrow = pt * 32 + ln;          // point row (B operand / H row)
    const int nn   = nt * 32 + ln;          // channel (A operand / W row)
    const int bidx = nt * 32 + 4 * q;       // bias frag base index

    // ---- stage L1/L2 biases (visibility via B1); issue global loads ----
    if (t < 128) {
        biasS[t]       = bias1[m * 128 + t];
        biasS[128 + t] = bias2[m * 128 + t];
    }
    const float* xp = x + (size_t)(b * 2048 + p0 + mrow) * 3;
    const float xv0 = xp[0], xv1 = xp[1], xv2 = xp[2];
    const u16* w0p = w0pl + (size_t)m * 4096 + q * 1024 + nn * 8;
    const v4u w0lo = *(const v4u*)(w0p);
    const v4u w0hi = *(const v4u*)(w0p + 2048);
    float4 b0f[4];
    #pragma unroll
    for (int gg = 0; gg < 4; ++gg)
        b0f[gg] = *(const float4*)(bias0 + m * 128 + bidx + 8 * gg);
    const float* zp = latent + ((size_t)m * 8 + block_idx[b]) * 13;
    float zr[8];
    #pragma unroll
    for (int j = 0; j < 8; ++j) zr[j] = zp[q * 5 + j];

    // epilogue write bases (4 consecutive n per group, 8 n between groups)
    u16* lop = Hlo + mrow * HSTRIDE + nt * 32 + 4 * q;
    u16* hip = Hhi + mrow * HSTRIDE + nt * 32 + 4 * q;

    // ---- layer 0: A = W0 (regs), B = input^T (regs), 3 products ----
    {
        float fin[8];
        if (q == 0) {
            fin[0] = xv0; fin[1] = xv1; fin[2] = xv2;
            #pragma unroll
            for (int j = 0; j < 5; ++j) fin[3 + j] = zr[j];
        } else {
            #pragma unroll
            for (int j = 0; j < 8; ++j) fin[j] = zr[j];
        }
        v4u il, ih;
        #pragma unroll
        for (int r = 0; r < 4; ++r) {
            u32 plo, phi;
            pk2(fin[2 * r], fin[2 * r + 1], plo, phi);
            il[r] = plo; ih[r] = phi;
        }
        const v8bf inlo = __builtin_bit_cast(v8bf, il);
        const v8bf inhi = __builtin_bit_cast(v8bf, ih);
        const v8bf wl = __builtin_bit_cast(v8bf, w0lo);
        const v8bf wh = __builtin_bit_cast(v8bf, w0hi);
        v16f acc;
        #pragma unroll
        for (int gg = 0; gg < 4; ++gg) {
            acc[4 * gg] = b0f[gg].x; acc[4 * gg + 1] = b0f[gg].y;
            acc[4 * gg + 2] = b0f[gg].z; acc[4 * gg + 3] = b0f[gg].w;
        }
        acc = MFMA(wl, inlo, acc);
        acc = MFMA(wl, inhi, acc);
        acc = MFMA(wh, inlo, acc);
        #pragma unroll
        for (int gg = 0; gg < 4; ++gg) {
            const float s0 = sin_omega(acc[4 * gg + 0]);
            const float s1 = sin_omega(acc[4 * gg + 1]);
            const float s2 = sin_omega(acc[4 * gg + 2]);
            const float s3 = sin_omega(acc[4 * gg + 3]);
            u32 l0, h0, l1, h1;
            pk2(s0, s1, l0, h0);
            pk2(s2, s3, l1, h1);
            v2u lov, hiv;
            lov[0] = l0; lov[1] = l1;
            hiv[0] = h0; hiv[1] = h1;
            *(v2u*)(lop + 8 * gg) = lov;
            *(v2u*)(hip + 8 * gg) = hiv;
        }
    }
    __syncthreads();  // B1: H(L0) + biasS visible

    // ---- layers 1,2: A = W (global, depth-2 rotated prefetch), B = H^T ----
    const u16* HLO = Hlo + mrow * HSTRIDE + q * 8;
    const u16* HHI = Hhi + mrow * HSTRIDE + q * 8;
    #pragma unroll 1
    for (int L = 0; L < 2; ++L) {
        const u16* Wb = (L ? wpl2 : wpl1) + (size_t)m * 32768 + q * 1024 + nn * 8;
        v16f acc;
        #pragma unroll
        for (int gg = 0; gg < 4; ++gg) {
            const float4 bv = *(const float4*)&biasS[L * 128 + bidx + 8 * gg];
            acc[4 * gg] = bv.x; acc[4 * gg + 1] = bv.y;
            acc[4 * gg + 2] = bv.z; acc[4 * gg + 3] = bv.w;
        }
        // depth-2 prefetch, 3-slot rotation (full unroll folds kc%3)
        v4u wlo[3], whi[3];
        wlo[0] = *(const v4u*)(Wb);
        whi[0] = *(const v4u*)(Wb + 16384);
        wlo[1] = *(const v4u*)(Wb + 2048);
        whi[1] = *(const v4u*)(Wb + 2048 + 16384);
        #pragma unroll
        for (int kc = 0; kc < 8; ++kc) {
            const int cur = kc % 3;
            if (kc < 6) {
                const int nxt = (kc + 2) % 3;
                wlo[nxt] = *(const v4u*)(Wb + (kc + 2) * 2048);
                whi[nxt] = *(const v4u*)(Wb + (kc + 2) * 2048 + 16384);
            }
            const v8bf hlo = *(const v8bf*)(HLO + kc * 16);
            const v8bf hhi = *(const v8bf*)(HHI + kc * 16);
            acc = MFMA(__builtin_bit_cast(v8bf, wlo[cur]), hlo, acc);
            acc = MFMA(__builtin_bit_cast(v8bf, wlo[cur]), hhi, acc);
            acc = MFMA(__builtin_bit_cast(v8bf, whi[cur]), hlo, acc);
        }
        __syncthreads();  // B2/B4: all H reads of this layer done
        #pragma unroll
        for (int gg = 0; gg < 4; ++gg) {
            const float s0 = sin_omega(acc[4 * gg + 0]);
            const float s1 = sin_omega(acc[4 * gg + 1]);
            const float s2 = sin_omega(acc[4 * gg + 2]);
            const float s3 = sin_omega(acc[4 * gg + 3]);
            u32 l0, h0, l1, h1;
            pk2(s0, s1, l0, h0);
            pk2(s2, s3, l1, h1);
            v2u lov, hiv;
            lov[0] = l0; lov[1] = l1;
            hiv[0] = h0; hiv[1] = h1;
            *(v2u*)(lop + 8 * gg) = lov;
            *(v2u*)(hip + 8 * gg) = hiv;
        }
        __syncthreads();  // B3/B5: H(L) visible
    }

    // ---- layer 3 on MFMA: A = w3 (broadcast), B = H^T; k-split by nt ----
    {
        const u16* w3b = w3pl + (size_t)m * 256 + nt * 32 + q * 8;
        const u16* h3l = Hlo + mrow * HSTRIDE + nt * 32 + q * 8;
        const u16* h3h = Hhi + mrow * HSTRIDE + nt * 32 + q * 8;
        v16f a3;
        #pragma unroll
        for (int r = 0; r < 16; ++r) a3[r] = 0.0f;
        #pragma unroll
        for (int kc = 0; kc < 2; ++kc) {
            const v8bf wl = *(const v8bf*)(w3b + kc * 16);
            const v8bf wh = *(const v8bf*)(w3b + 128 + kc * 16);
            const v8bf hl = *(const v8bf*)(h3l + kc * 16);
            const v8bf hh = *(const v8bf*)(h3h + kc * 16);
            a3 = MFMA(wl, hl, a3);
            a3 = MFMA(wl, hh, a3);
            a3 = MFMA(wh, hl, a3);
        }
        if (q == 0) red[pt * 128 + nt * 32 + ln] = a3[0];
    }
    __syncthreads();  // B6

    if (t < 64) {
        const int rp = (t >> 5) * 128, rl = t & 31;
        const float o = bias3[m]
            + red[rp + rl] + red[rp + 32 + rl]
            + red[rp + 64 + rl] + red[rp + 96 + rl];
        out[(size_t)b * 2048 + p0 + t] = o;
    }
}

extern "C" void kernel_launch(void* const* d_in, const int* in_sizes, int n_in,
                              void* d_out, int out_size, void* d_ws, size_t ws_size,
                              hipStream_t stream) {
    (void)in_sizes; (void)n_in; (void)out_size; (void)ws_size;
    u16* wpl1 = (u16*)d_ws;                        // 16 MB
    u16* wpl2 = wpl1 + (size_t)256 * 32768;        // 16 MB
    u16* w0pl = wpl2 + (size_t)256 * 32768;        // 2 MB
    u16* w3pl = w0pl + (size_t)256 * 4096;         // 128 KB

    ecnr_dequant<<<768, 512, 0, stream>>>(
        (const float*)d_in[4],  (const int*)d_in[5],
        (const float*)d_in[7],  (const int*)d_in[8],
        (const float*)d_in[10], (const int*)d_in[11],
        (const float*)d_in[13], (const int*)d_in[14],
        wpl1, wpl2, w0pl, w3pl);

    ecnr_fwd<<<8192, 512, 0, stream>>>(
        (const float*)d_in[0], (const int*)d_in[1], (const int*)d_in[2],
        (const float*)d_in[3],
        (const float*)d_in[6], (const float*)d_in[9],
        (const float*)d_in[12], (const float*)d_in[15],
        wpl1, wpl2, w0pl, w3pl,
        (float*)d_out);
}

// Round 15
// 238.118 us; speedup vs baseline: 1.6674x; 1.0302x over previous
//
#include <hip/hip_runtime.h>

// ECNR forward, R15 = R14 with:
//  (a) W-lo panel fully register-resident: all 8 wlo frags (32 VGPR) loaded
//      before the kc-loop (one amortized L2 wait/layer, was 8 exposed);
//      whi issued at iter top, covered by 2 ds_reads + 2 MFMAs + 8-wave TLP.
//  (b) L2->L3 handoff bf16-lo only (L3 output not sin-amplified; adds ~1e-3
//      RMS): L2 epilogue writes lo plane only, L3 uses 4 MFMA (drops hh).
//  Numerics otherwise identical to R14: absmax ~0.028-0.033 expected.

typedef unsigned int u32;
typedef unsigned short u16;
typedef __bf16 v8bf  __attribute__((ext_vector_type(8)));
typedef __bf16 v2bf  __attribute__((ext_vector_type(2)));
typedef float  v16f  __attribute__((ext_vector_type(16)));
typedef float  v2f   __attribute__((ext_vector_type(2)));
typedef u32    v4u   __attribute__((ext_vector_type(4)));
typedef u32    v2u   __attribute__((ext_vector_type(2)));

#define MFMA(a, b, c) __builtin_amdgcn_mfma_f32_32x32x16_bf16(a, b, c, 0, 0, 0)

#define HSTRIDE 136   // u16; 272 B rows: 16B-aligned, bank-balanced

__device__ __forceinline__ float sin_omega(float pre) {
    float rev = pre * 4.774648292756860f;
    return __builtin_amdgcn_sinf(__builtin_amdgcn_fractf(rev));
}

__device__ __forceinline__ u32 pack2(float c) {
    __bf16 b0 = (__bf16)c;
    float  f0 = (float)b0;
    __bf16 b1 = (__bf16)(c - f0);
    return (u32)__builtin_bit_cast(u16, b0) |
           ((u32)__builtin_bit_cast(u16, b1) << 16);
}

// two floats -> packed lo (bf16x2) and packed hi (residual bf16x2), RNE
__device__ __forceinline__ void pk2(float s0, float s1, u32& lo, u32& hi) {
    v2f s; s[0] = s0; s[1] = s1;
    v2bf l = __builtin_convertvector(s, v2bf);        // v_cvt_pk_bf16_f32
    u32 lov = __builtin_bit_cast(u32, l);
    v2f lf;
    lf[0] = __builtin_bit_cast(float, lov << 16);
    lf[1] = __builtin_bit_cast(float, lov & 0xffff0000u);
    v2f r = s - lf;
    v2bf h = __builtin_convertvector(r, v2bf);
    lo = lov;
    hi = __builtin_bit_cast(u32, h);
}

// two floats -> packed lo only
__device__ __forceinline__ u32 pklo(float s0, float s1) {
    v2f s; s[0] = s0; s[1] = s1;
    v2bf l = __builtin_convertvector(s, v2bf);
    return __builtin_bit_cast(u32, l);
}

#define PLO(a, b) __builtin_amdgcn_perm((a), (b), 0x05040100u)
#define PHI(a, b) __builtin_amdgcn_perm((a), (b), 0x07060302u)

// ---------------------------------------------------------------------------
// K1: dequant (unchanged from R8-R14).
// ---------------------------------------------------------------------------
__global__ __launch_bounds__(512)
void ecnr_dequant(const float* __restrict__ cent0, const int* __restrict__ lab0,
                  const float* __restrict__ cent1, const int* __restrict__ lab1,
                  const float* __restrict__ cent2, const int* __restrict__ lab2,
                  const float* __restrict__ cent3, const int* __restrict__ lab3,
                  u16* __restrict__ wpl1, u16* __restrict__ wpl2,
                  u16* __restrict__ w0pl, u16* __restrict__ w3pl)
{
    __shared__ u32 cpk[512];
    const int t = threadIdx.x;

    if (blockIdx.x < 512) {
        const int m = blockIdx.x >> 1, L = blockIdx.x & 1;
        if (t < 256) cpk[t] = pack2((L ? cent2 : cent1)[t]);
        __syncthreads();
        const int* lab = (L ? lab2 : lab1) + (size_t)m * 16384;
        u16* base = (L ? wpl2 : wpl1) + (size_t)m * 32768;
        #pragma unroll
        for (int i = 0; i < 4; ++i) {
            const int id = i * 512 + t;
            const int n = id & 127, c = id >> 7;
            u32 g[8];
            #pragma unroll
            for (int j = 0; j < 8; ++j) g[j] = cpk[lab[(8 * c + j) * 128 + n]];
            v4u lo, hi;
            #pragma unroll
            for (int r = 0; r < 4; ++r) {
                lo[r] = PLO(g[2 * r + 1], g[2 * r]);
                hi[r] = PHI(g[2 * r + 1], g[2 * r]);
            }
            *(v4u*)(base + c * 1024 + n * 8)         = lo;
            *(v4u*)(base + 16384 + c * 1024 + n * 8) = hi;
        }
    } else {
        const int m = blockIdx.x - 512;
        if (t < 256) cpk[t] = pack2(cent0[t]);
        else         cpk[t] = pack2(cent3[t - 256]);
        __syncthreads();
        if (t < 256) {
            const int n = t & 127, c = t >> 7;
            const int* lab = lab0 + (size_t)m * 2048;
            u32 g[8];
            #pragma unroll
            for (int j = 0; j < 8; ++j) g[j] = cpk[lab[(8 * c + j) * 128 + n]];
            v4u lo, hi;
            #pragma unroll
            for (int r = 0; r < 4; ++r) {
                lo[r] = PLO(g[2 * r + 1], g[2 * r]);
                hi[r] = PHI(g[2 * r + 1], g[2 * r]);
            }
            u16* b0 = w0pl + (size_t)m * 4096;
            *(v4u*)(b0 + c * 1024 + n * 8)        = lo;
            *(v4u*)(b0 + 2048 + c * 1024 + n * 8) = hi;
        } else if (t < 384) {
            const int kk = t - 256;
            const u32 u = cpk[256 + lab3[(size_t)m * 128 + kk]];
            w3pl[(size_t)m * 256 + kk]       = (u16)u;
            w3pl[(size_t)m * 256 + 128 + kk] = (u16)(u >> 16);
        }
    }
}

// ---------------------------------------------------------------------------
// K2: fused forward. LDS: Hlo/Hhi 2x17408 + biasS 1024 + red 1024 = 36864 B.
// ---------------------------------------------------------------------------
__global__ __launch_bounds__(512, 8)
void ecnr_fwd(const float* __restrict__ x,
              const int*   __restrict__ mlp_idx,
              const int*   __restrict__ block_idx,
              const float* __restrict__ latent,
              const float* __restrict__ bias0, const float* __restrict__ bias1,
              const float* __restrict__ bias2, const float* __restrict__ bias3,
              const u16* __restrict__ wpl1, const u16* __restrict__ wpl2,
              const u16* __restrict__ w0pl, const u16* __restrict__ w3pl,
              float* __restrict__ out)
{
    __shared__ __attribute__((aligned(16))) u16   Hlo[64 * HSTRIDE];
    __shared__ __attribute__((aligned(16))) u16   Hhi[64 * HSTRIDE];
    __shared__ __attribute__((aligned(16))) float biasS[2 * 128];
    __shared__ __attribute__((aligned(16))) float red[2 * 128];

    // XCD swizzle (bijective): xcd=g[2:0], tile=g[7:3], sample=g[12:8]<<3|xcd
    const int g    = blockIdx.x;
    const int b    = ((g >> 8) << 3) | (g & 7);    // sample 0..255
    const int p0   = ((g >> 3) & 31) * 64;         // tile * 64
    const int m    = mlp_idx[b];

    const int t  = threadIdx.x;
    const int l  = t & 63, w = t >> 6;
    const int q  = l >> 5, ln = l & 31;
    const int pt = w & 1, nt = w >> 1;      // 2 pt x 4 nt tiles of 32x32
    const int mrow = pt * 32 + ln;          // point row (B operand / H row)
    const int nn   = nt * 32 + ln;          // channel (A operand / W row)
    const int bidx = nt * 32 + 4 * q;       // bias frag base index

    // ---- stage L1/L2 biases (visibility via B1); issue global loads ----
    if (t < 128) {
        biasS[t]       = bias1[m * 128 + t];
        biasS[128 + t] = bias2[m * 128 + t];
    }
    const float* xp = x + (size_t)(b * 2048 + p0 + mrow) * 3;
    const float xv0 = xp[0], xv1 = xp[1], xv2 = xp[2];
    const u16* w0p = w0pl + (size_t)m * 4096 + q * 1024 + nn * 8;
    const v4u w0lo = *(const v4u*)(w0p);
    const v4u w0hi = *(const v4u*)(w0p + 2048);
    float4 b0f[4];
    #pragma unroll
    for (int gg = 0; gg < 4; ++gg)
        b0f[gg] = *(const float4*)(bias0 + m * 128 + bidx + 8 * gg);
    const float* zp = latent + ((size_t)m * 8 + block_idx[b]) * 13;
    float zr[8];
    #pragma unroll
    for (int j = 0; j < 8; ++j) zr[j] = zp[q * 5 + j];

    // epilogue write bases (4 consecutive n per group, 8 n between groups)
    u16* lop = Hlo + mrow * HSTRIDE + nt * 32 + 4 * q;
    u16* hip = Hhi + mrow * HSTRIDE + nt * 32 + 4 * q;

    // ---- layer 0: A = W0 (regs), B = input^T (regs), 3 products ----
    {
        float fin[8];
        if (q == 0) {
            fin[0] = xv0; fin[1] = xv1; fin[2] = xv2;
            #pragma unroll
            for (int j = 0; j < 5; ++j) fin[3 + j] = zr[j];
        } else {
            #pragma unroll
            for (int j = 0; j < 8; ++j) fin[j] = zr[j];
        }
        v4u il, ih;
        #pragma unroll
        for (int r = 0; r < 4; ++r) {
            u32 plo, phi;
            pk2(fin[2 * r], fin[2 * r + 1], plo, phi);
            il[r] = plo; ih[r] = phi;
        }
        const v8bf inlo = __builtin_bit_cast(v8bf, il);
        const v8bf inhi = __builtin_bit_cast(v8bf, ih);
        const v8bf wl = __builtin_bit_cast(v8bf, w0lo);
        const v8bf wh = __builtin_bit_cast(v8bf, w0hi);
        v16f acc;
        #pragma unroll
        for (int gg = 0; gg < 4; ++gg) {
            acc[4 * gg] = b0f[gg].x; acc[4 * gg + 1] = b0f[gg].y;
            acc[4 * gg + 2] = b0f[gg].z; acc[4 * gg + 3] = b0f[gg].w;
        }
        acc = MFMA(wl, inlo, acc);
        acc = MFMA(wl, inhi, acc);
        acc = MFMA(wh, inlo, acc);
        #pragma unroll
        for (int gg = 0; gg < 4; ++gg) {
            const float s0 = sin_omega(acc[4 * gg + 0]);
            const float s1 = sin_omega(acc[4 * gg + 1]);
            const float s2 = sin_omega(acc[4 * gg + 2]);
            const float s3 = sin_omega(acc[4 * gg + 3]);
            u32 l0, h0, l1, h1;
            pk2(s0, s1, l0, h0);
            pk2(s2, s3, l1, h1);
            v2u lov, hiv;
            lov[0] = l0; lov[1] = l1;
            hiv[0] = h0; hiv[1] = h1;
            *(v2u*)(lop + 8 * gg) = lov;
            *(v2u*)(hip + 8 * gg) = hiv;
        }
    }
    __syncthreads();  // B1: H(L0) + biasS visible

    // ---- layers 1,2: A = W (wlo panel register-resident), B = H^T (LDS) ----
    const u16* HLO = Hlo + mrow * HSTRIDE + q * 8;
    const u16* HHI = Hhi + mrow * HSTRIDE + q * 8;
    #pragma unroll 1
    for (int L = 0; L < 2; ++L) {
        const u16* Wb = (L ? wpl2 : wpl1) + (size_t)m * 32768 + q * 1024 + nn * 8;
        v16f acc;
        #pragma unroll
        for (int gg = 0; gg < 4; ++gg) {
            const float4 bv = *(const float4*)&biasS[L * 128 + bidx + 8 * gg];
            acc[4 * gg] = bv.x; acc[4 * gg + 1] = bv.y;
            acc[4 * gg + 2] = bv.z; acc[4 * gg + 3] = bv.w;
        }
        // all 8 wlo fragments register-resident (32 VGPR); one L2 wait/layer
        v4u wl8[8];
        #pragma unroll
        for (int kc = 0; kc < 8; ++kc)
            wl8[kc] = *(const v4u*)(Wb + kc * 2048);
        #pragma unroll
        for (int kc = 0; kc < 8; ++kc) {
            const v4u whv = *(const v4u*)(Wb + kc * 2048 + 16384);  // issue early
            const v8bf hlo = *(const v8bf*)(HLO + kc * 16);
            const v8bf hhi = *(const v8bf*)(HHI + kc * 16);
            acc = MFMA(__builtin_bit_cast(v8bf, wl8[kc]), hlo, acc);
            acc = MFMA(__builtin_bit_cast(v8bf, wl8[kc]), hhi, acc);
            acc = MFMA(__builtin_bit_cast(v8bf, whv), hlo, acc);
        }
        __syncthreads();  // B2/B4: all H reads of this layer done
        if (L == 0) {
            #pragma unroll
            for (int gg = 0; gg < 4; ++gg) {
                const float s0 = sin_omega(acc[4 * gg + 0]);
                const float s1 = sin_omega(acc[4 * gg + 1]);
                const float s2 = sin_omega(acc[4 * gg + 2]);
                const float s3 = sin_omega(acc[4 * gg + 3]);
                u32 l0, h0, l1, h1;
                pk2(s0, s1, l0, h0);
                pk2(s2, s3, l1, h1);
                v2u lov, hiv;
                lov[0] = l0; lov[1] = l1;
                hiv[0] = h0; hiv[1] = h1;
                *(v2u*)(lop + 8 * gg) = lov;
                *(v2u*)(hip + 8 * gg) = hiv;
            }
        } else {  // L2 -> L3 handoff: lo plane only (L3 not sin-amplified)
            #pragma unroll
            for (int gg = 0; gg < 4; ++gg) {
                const float s0 = sin_omega(acc[4 * gg + 0]);
                const float s1 = sin_omega(acc[4 * gg + 1]);
                const float s2 = sin_omega(acc[4 * gg + 2]);
                const float s3 = sin_omega(acc[4 * gg + 3]);
                v2u lov;
                lov[0] = pklo(s0, s1);
                lov[1] = pklo(s2, s3);
                *(v2u*)(lop + 8 * gg) = lov;
            }
        }
        __syncthreads();  // B3/B5: H(L) visible
    }

    // ---- layer 3 on MFMA: A = w3 (bf16x2), B = H^T lo; k-split by nt ----
    {
        const u16* w3b = w3pl + (size_t)m * 256 + nt * 32 + q * 8;
        const u16* h3l = Hlo + mrow * HSTRIDE + nt * 32 + q * 8;
        v16f a3;
        #pragma unroll
        for (int r = 0; r < 16; ++r) a3[r] = 0.0f;
        #pragma unroll
        for (int kc = 0; kc < 2; ++kc) {
            const v8bf wl = *(const v8bf*)(w3b + kc * 16);
            const v8bf wh = *(const v8bf*)(w3b + 128 + kc * 16);
            const v8bf hl = *(const v8bf*)(h3l + kc * 16);
            a3 = MFMA(wl, hl, a3);
            a3 = MFMA(wh, hl, a3);
        }
        if (q == 0) red[pt * 128 + nt * 32 + ln] = a3[0];
    }
    __syncthreads();  // B6

    if (t < 64) {
        const int rp = (t >> 5) * 128, rl = t & 31;
        const float o = bias3[m]
            + red[rp + rl] + red[rp + 32 + rl]
            + red[rp + 64 + rl] + red[rp + 96 + rl];
        out[(size_t)b * 2048 + p0 + t] = o;
    }
}

extern "C" void kernel_launch(void* const* d_in, const int* in_sizes, int n_in,
                              void* d_out, int out_size, void* d_ws, size_t ws_size,
                              hipStream_t stream) {
    (void)in_sizes; (void)n_in; (void)out_size; (void)ws_size;
    u16* wpl1 = (u16*)d_ws;                        // 16 MB
    u16* wpl2 = wpl1 + (size_t)256 * 32768;        // 16 MB
    u16* w0pl = wpl2 + (size_t)256 * 32768;        // 2 MB
    u16* w3pl = w0pl + (size_t)256 * 4096;         // 128 KB

    ecnr_dequant<<<768, 512, 0, stream>>>(
        (const float*)d_in[4],  (const int*)d_in[5],
        (const float*)d_in[7],  (const int*)d_in[8],
        (const float*)d_in[10], (const int*)d_in[11],
        (const float*)d_in[13], (const int*)d_in[14],
        wpl1, wpl2, w0pl, w3pl);

    ecnr_fwd<<<8192, 512, 0, stream>>>(
        (const float*)d_in[0], (const int*)d_in[1], (const int*)d_in[2],
        (const float*)d_in[3],
        (const float*)d_in[6], (const float*)d_in[9],
        (const float*)d_in[12], (const float*)d_in[15],
        wpl1, wpl2, w0pl, w3pl,
        (float*)d_out);
}

// Round 16
// 236.820 us; speedup vs baseline: 1.6765x; 1.0055x over previous
//
#include <hip/hip_runtime.h>

// ECNR forward, R16 = R15 with omega pre-scaling:
//  Weights of L0/L1/L2 and their biases are pre-multiplied by s = 30/(2*pi)
//  at dequant time, so the MFMA accumulator directly holds REVOLUTIONS:
//  epilogue sin becomes v_fract + v_sin (deletes 48 v_mul/thread, ~26% of
//  the sin-chain VALU). L3 weights/bias stay unscaled (no sin).
//  Everything else identical to R15 (139.6 us fwd, absmax 0.02734375).

typedef unsigned int u32;
typedef unsigned short u16;
typedef __bf16 v8bf  __attribute__((ext_vector_type(8)));
typedef __bf16 v2bf  __attribute__((ext_vector_type(2)));
typedef float  v16f  __attribute__((ext_vector_type(16)));
typedef float  v2f   __attribute__((ext_vector_type(2)));
typedef u32    v4u   __attribute__((ext_vector_type(4)));
typedef u32    v2u   __attribute__((ext_vector_type(2)));

#define MFMA(a, b, c) __builtin_amdgcn_mfma_f32_32x32x16_bf16(a, b, c, 0, 0, 0)

#define HSTRIDE 136                 // u16; 272 B rows: 16B-aligned, bank-balanced
#define OMEGA_S 4.774648292756860f  // 30/(2*pi); identical constant in both kernels

// acc already in revolutions: sin = v_sin(v_fract(acc))
__device__ __forceinline__ float sinrev(float rev) {
    return __builtin_amdgcn_sinf(__builtin_amdgcn_fractf(rev));
}

__device__ __forceinline__ u32 pack2(float c) {
    __bf16 b0 = (__bf16)c;
    float  f0 = (float)b0;
    __bf16 b1 = (__bf16)(c - f0);
    return (u32)__builtin_bit_cast(u16, b0) |
           ((u32)__builtin_bit_cast(u16, b1) << 16);
}

// two floats -> packed lo (bf16x2) and packed hi (residual bf16x2), RNE
__device__ __forceinline__ void pk2(float s0, float s1, u32& lo, u32& hi) {
    v2f s; s[0] = s0; s[1] = s1;
    v2bf l = __builtin_convertvector(s, v2bf);        // v_cvt_pk_bf16_f32
    u32 lov = __builtin_bit_cast(u32, l);
    v2f lf;
    lf[0] = __builtin_bit_cast(float, lov << 16);
    lf[1] = __builtin_bit_cast(float, lov & 0xffff0000u);
    v2f r = s - lf;
    v2bf h = __builtin_convertvector(r, v2bf);
    lo = lov;
    hi = __builtin_bit_cast(u32, h);
}

__device__ __forceinline__ u32 pklo(float s0, float s1) {
    v2f s; s[0] = s0; s[1] = s1;
    v2bf l = __builtin_convertvector(s, v2bf);
    return __builtin_bit_cast(u32, l);
}

#define PLO(a, b) __builtin_amdgcn_perm((a), (b), 0x05040100u)
#define PHI(a, b) __builtin_amdgcn_perm((a), (b), 0x07060302u)

// ---------------------------------------------------------------------------
// K1: dequant. L0/L1/L2 centroids scaled by OMEGA_S; scaled biases -> biasc.
// ---------------------------------------------------------------------------
__global__ __launch_bounds__(512)
void ecnr_dequant(const float* __restrict__ cent0, const int* __restrict__ lab0,
                  const float* __restrict__ cent1, const int* __restrict__ lab1,
                  const float* __restrict__ cent2, const int* __restrict__ lab2,
                  const float* __restrict__ cent3, const int* __restrict__ lab3,
                  const float* __restrict__ bias0, const float* __restrict__ bias1,
                  const float* __restrict__ bias2,
                  u16* __restrict__ wpl1, u16* __restrict__ wpl2,
                  u16* __restrict__ w0pl, u16* __restrict__ w3pl,
                  float* __restrict__ biasc)
{
    __shared__ u32 cpk[512];
    const int t = threadIdx.x;

    if (blockIdx.x < 512) {
        const int m = blockIdx.x >> 1, L = blockIdx.x & 1;
        if (t < 256) cpk[t] = pack2((L ? cent2 : cent1)[t] * OMEGA_S);
        __syncthreads();
        const int* lab = (L ? lab2 : lab1) + (size_t)m * 16384;
        u16* base = (L ? wpl2 : wpl1) + (size_t)m * 32768;
        #pragma unroll
        for (int i = 0; i < 4; ++i) {
            const int id = i * 512 + t;
            const int n = id & 127, c = id >> 7;
            u32 g[8];
            #pragma unroll
            for (int j = 0; j < 8; ++j) g[j] = cpk[lab[(8 * c + j) * 128 + n]];
            v4u lo, hi;
            #pragma unroll
            for (int r = 0; r < 4; ++r) {
                lo[r] = PLO(g[2 * r + 1], g[2 * r]);
                hi[r] = PHI(g[2 * r + 1], g[2 * r]);
            }
            *(v4u*)(base + c * 1024 + n * 8)         = lo;
            *(v4u*)(base + 16384 + c * 1024 + n * 8) = hi;
        }
    } else {
        const int m = blockIdx.x - 512;
        if (t < 256) cpk[t] = pack2(cent0[t] * OMEGA_S);
        else         cpk[t] = pack2(cent3[t - 256]);    // L3 unscaled
        __syncthreads();
        if (t < 256) {
            const int n = t & 127, c = t >> 7;
            const int* lab = lab0 + (size_t)m * 2048;
            u32 g[8];
            #pragma unroll
            for (int j = 0; j < 8; ++j) g[j] = cpk[lab[(8 * c + j) * 128 + n]];
            v4u lo, hi;
            #pragma unroll
            for (int r = 0; r < 4; ++r) {
                lo[r] = PLO(g[2 * r + 1], g[2 * r]);
                hi[r] = PHI(g[2 * r + 1], g[2 * r]);
            }
            u16* b0 = w0pl + (size_t)m * 4096;
            *(v4u*)(b0 + c * 1024 + n * 8)        = lo;
            *(v4u*)(b0 + 2048 + c * 1024 + n * 8) = hi;
        } else if (t < 384) {
            const int kk = t - 256;
            const u32 u = cpk[256 + lab3[(size_t)m * 128 + kk]];
            w3pl[(size_t)m * 256 + kk]       = (u16)u;
            w3pl[(size_t)m * 256 + 128 + kk] = (u16)(u >> 16);
        }
        // scaled biases: biasc[m][0..127]=b0*s, [128..255]=b1*s, [256..383]=b2*s
        if (t < 384) {
            const int li = t >> 7, kk = t & 127;
            const float* bsrc = (li == 0) ? bias0 : (li == 1) ? bias1 : bias2;
            biasc[(size_t)m * 384 + t] = bsrc[m * 128 + kk] * OMEGA_S;
        }
    }
}

// ---------------------------------------------------------------------------
// K2: fused forward. LDS: Hlo/Hhi 2x17408 + biasS 1024 + red 1024 = 36864 B.
// ---------------------------------------------------------------------------
__global__ __launch_bounds__(512, 8)
void ecnr_fwd(const float* __restrict__ x,
              const int*   __restrict__ mlp_idx,
              const int*   __restrict__ block_idx,
              const float* __restrict__ latent,
              const float* __restrict__ bias3,
              const u16* __restrict__ wpl1, const u16* __restrict__ wpl2,
              const u16* __restrict__ w0pl, const u16* __restrict__ w3pl,
              const float* __restrict__ biasc,
              float* __restrict__ out)
{
    __shared__ __attribute__((aligned(16))) u16   Hlo[64 * HSTRIDE];
    __shared__ __attribute__((aligned(16))) u16   Hhi[64 * HSTRIDE];
    __shared__ __attribute__((aligned(16))) float biasS[2 * 128];
    __shared__ __attribute__((aligned(16))) float red[2 * 128];

    // XCD swizzle (bijective): xcd=g[2:0], tile=g[7:3], sample=g[12:8]<<3|xcd
    const int g    = blockIdx.x;
    const int b    = ((g >> 8) << 3) | (g & 7);    // sample 0..255
    const int p0   = ((g >> 3) & 31) * 64;         // tile * 64
    const int m    = mlp_idx[b];

    const int t  = threadIdx.x;
    const int l  = t & 63, w = t >> 6;
    const int q  = l >> 5, ln = l & 31;
    const int pt = w & 1, nt = w >> 1;      // 2 pt x 4 nt tiles of 32x32
    const int mrow = pt * 32 + ln;          // point row (B operand / H row)
    const int nn   = nt * 32 + ln;          // channel (A operand / W row)
    const int bidx = nt * 32 + 4 * q;       // bias frag base index

    const float* bc = biasc + (size_t)m * 384;
    // ---- stage L1/L2 scaled biases (visibility via B1); global loads ----
    if (t < 128) {
        biasS[t]       = bc[128 + t];
        biasS[128 + t] = bc[256 + t];
    }
    const float* xp = x + (size_t)(b * 2048 + p0 + mrow) * 3;
    const float xv0 = xp[0], xv1 = xp[1], xv2 = xp[2];
    const u16* w0p = w0pl + (size_t)m * 4096 + q * 1024 + nn * 8;
    const v4u w0lo = *(const v4u*)(w0p);
    const v4u w0hi = *(const v4u*)(w0p + 2048);
    float4 b0f[4];
    #pragma unroll
    for (int gg = 0; gg < 4; ++gg)
        b0f[gg] = *(const float4*)(bc + bidx + 8 * gg);
    const float* zp = latent + ((size_t)m * 8 + block_idx[b]) * 13;
    float zr[8];
    #pragma unroll
    for (int j = 0; j < 8; ++j) zr[j] = zp[q * 5 + j];

    // epilogue write bases (4 consecutive n per group, 8 n between groups)
    u16* lop = Hlo + mrow * HSTRIDE + nt * 32 + 4 * q;
    u16* hip = Hhi + mrow * HSTRIDE + nt * 32 + 4 * q;

    // ---- layer 0: A = W0 (regs, scaled), B = input^T (regs), 3 products ----
    {
        float fin[8];
        if (q == 0) {
            fin[0] = xv0; fin[1] = xv1; fin[2] = xv2;
            #pragma unroll
            for (int j = 0; j < 5; ++j) fin[3 + j] = zr[j];
        } else {
            #pragma unroll
            for (int j = 0; j < 8; ++j) fin[j] = zr[j];
        }
        v4u il, ih;
        #pragma unroll
        for (int r = 0; r < 4; ++r) {
            u32 plo, phi;
            pk2(fin[2 * r], fin[2 * r + 1], plo, phi);
            il[r] = plo; ih[r] = phi;
        }
        const v8bf inlo = __builtin_bit_cast(v8bf, il);
        const v8bf inhi = __builtin_bit_cast(v8bf, ih);
        const v8bf wl = __builtin_bit_cast(v8bf, w0lo);
        const v8bf wh = __builtin_bit_cast(v8bf, w0hi);
        v16f acc;
        #pragma unroll
        for (int gg = 0; gg < 4; ++gg) {
            acc[4 * gg] = b0f[gg].x; acc[4 * gg + 1] = b0f[gg].y;
            acc[4 * gg + 2] = b0f[gg].z; acc[4 * gg + 3] = b0f[gg].w;
        }
        acc = MFMA(wl, inlo, acc);
        acc = MFMA(wl, inhi, acc);
        acc = MFMA(wh, inlo, acc);
        #pragma unroll
        for (int gg = 0; gg < 4; ++gg) {
            const float s0 = sinrev(acc[4 * gg + 0]);
            const float s1 = sinrev(acc[4 * gg + 1]);
            const float s2 = sinrev(acc[4 * gg + 2]);
            const float s3 = sinrev(acc[4 * gg + 3]);
            u32 l0, h0, l1, h1;
            pk2(s0, s1, l0, h0);
            pk2(s2, s3, l1, h1);
            v2u lov, hiv;
            lov[0] = l0; lov[1] = l1;
            hiv[0] = h0; hiv[1] = h1;
            *(v2u*)(lop + 8 * gg) = lov;
            *(v2u*)(hip + 8 * gg) = hiv;
        }
    }
    __syncthreads();  // B1: H(L0) + biasS visible

    // ---- layers 1,2: A = W (wlo panel resident), B = H^T (LDS) ----
    const u16* HLO = Hlo + mrow * HSTRIDE + q * 8;
    const u16* HHI = Hhi + mrow * HSTRIDE + q * 8;
    #pragma unroll 1
    for (int L = 0; L < 2; ++L) {
        const u16* Wb = (L ? wpl2 : wpl1) + (size_t)m * 32768 + q * 1024 + nn * 8;
        v16f acc;
        #pragma unroll
        for (int gg = 0; gg < 4; ++gg) {
            const float4 bv = *(const float4*)&biasS[L * 128 + bidx + 8 * gg];
            acc[4 * gg] = bv.x; acc[4 * gg + 1] = bv.y;
            acc[4 * gg + 2] = bv.z; acc[4 * gg + 3] = bv.w;
        }
        v4u wl8[8];
        #pragma unroll
        for (int kc = 0; kc < 8; ++kc)
            wl8[kc] = *(const v4u*)(Wb + kc * 2048);
        #pragma unroll
        for (int kc = 0; kc < 8; ++kc) {
            const v4u whv = *(const v4u*)(Wb + kc * 2048 + 16384);  // issue early
            const v8bf hlo = *(const v8bf*)(HLO + kc * 16);
            const v8bf hhi = *(const v8bf*)(HHI + kc * 16);
            acc = MFMA(__builtin_bit_cast(v8bf, wl8[kc]), hlo, acc);
            acc = MFMA(__builtin_bit_cast(v8bf, wl8[kc]), hhi, acc);
            acc = MFMA(__builtin_bit_cast(v8bf, whv), hlo, acc);
        }
        __syncthreads();  // B2/B4: all H reads of this layer done
        if (L == 0) {
            #pragma unroll
            for (int gg = 0; gg < 4; ++gg) {
                const float s0 = sinrev(acc[4 * gg + 0]);
                const float s1 = sinrev(acc[4 * gg + 1]);
                const float s2 = sinrev(acc[4 * gg + 2]);
                const float s3 = sinrev(acc[4 * gg + 3]);
                u32 l0, h0, l1, h1;
                pk2(s0, s1, l0, h0);
                pk2(s2, s3, l1, h1);
                v2u lov, hiv;
                lov[0] = l0; lov[1] = l1;
                hiv[0] = h0; hiv[1] = h1;
                *(v2u*)(lop + 8 * gg) = lov;
                *(v2u*)(hip + 8 * gg) = hiv;
            }
        } else {  // L2 -> L3 handoff: lo plane only (L3 not sin-amplified)
            #pragma unroll
            for (int gg = 0; gg < 4; ++gg) {
                const float s0 = sinrev(acc[4 * gg + 0]);
                const float s1 = sinrev(acc[4 * gg + 1]);
                const float s2 = sinrev(acc[4 * gg + 2]);
                const float s3 = sinrev(acc[4 * gg + 3]);
                v2u lov;
                lov[0] = pklo(s0, s1);
                lov[1] = pklo(s2, s3);
                *(v2u*)(lop + 8 * gg) = lov;
            }
        }
        __syncthreads();  // B3/B5: H(L) visible
    }

    // ---- layer 3 on MFMA: A = w3 (bf16x2, unscaled), B = H^T lo ----
    {
        const u16* w3b = w3pl + (size_t)m * 256 + nt * 32 + q * 8;
        const u16* h3l = Hlo + mrow * HSTRIDE + nt * 32 + q * 8;
        v16f a3;
        #pragma unroll
        for (int r = 0; r < 16; ++r) a3[r] = 0.0f;
        #pragma unroll
        for (int kc = 0; kc < 2; ++kc) {
            const v8bf wl = *(const v8bf*)(w3b + kc * 16);
            const v8bf wh = *(const v8bf*)(w3b + 128 + kc * 16);
            const v8bf hl = *(const v8bf*)(h3l + kc * 16);
            a3 = MFMA(wl, hl, a3);
            a3 = MFMA(wh, hl, a3);
        }
        if (q == 0) red[pt * 128 + nt * 32 + ln] = a3[0];
    }
    __syncthreads();  // B6

    if (t < 64) {
        const int rp = (t >> 5) * 128, rl = t & 31;
        const float o = bias3[m]
            + red[rp + rl] + red[rp + 32 + rl]
            + red[rp + 64 + rl] + red[rp + 96 + rl];
        out[(size_t)b * 2048 + p0 + t] = o;
    }
}

extern "C" void kernel_launch(void* const* d_in, const int* in_sizes, int n_in,
                              void* d_out, int out_size, void* d_ws, size_t ws_size,
                              hipStream_t stream) {
    (void)in_sizes; (void)n_in; (void)out_size; (void)ws_size;
    u16*   wpl1  = (u16*)d_ws;                          // 16 MB
    u16*   wpl2  = wpl1 + (size_t)256 * 32768;          // 16 MB
    u16*   w0pl  = wpl2 + (size_t)256 * 32768;          // 2 MB
    u16*   w3pl  = w0pl + (size_t)256 * 4096;           // 128 KB
    float* biasc = (float*)(w3pl + (size_t)256 * 256);  // 384 KB (scaled biases)

    ecnr_dequant<<<768, 512, 0, stream>>>(
        (const float*)d_in[4],  (const int*)d_in[5],
        (const float*)d_in[7],  (const int*)d_in[8],
        (const float*)d_in[10], (const int*)d_in[11],
        (const float*)d_in[13], (const int*)d_in[14],
        (const float*)d_in[6],  (const float*)d_in[9], (const float*)d_in[12],
        wpl1, wpl2, w0pl, w3pl, biasc);

    ecnr_fwd<<<8192, 512, 0, stream>>>(
        (const float*)d_in[0], (const int*)d_in[1], (const int*)d_in[2],
        (const float*)d_in[3],
        (const float*)d_in[15],
        wpl1, wpl2, w0pl, w3pl, biasc,
        (float*)d_out);
}